// Round 11
// baseline (450.249 us; speedup 1.0000x reference)
//
#include <hip/hip_runtime.h>
#include <hip/hip_bf16.h>

#define N_CRYST 256
#define ATOMS_PER 64
#define N_ATOMS (N_CRYST * ATOMS_PER)   // 16384
#define N_EDGES (N_ATOMS * 20)          // 327680
#define HID 128
#define LAT 256
#define NRAD 128
#define NBLOCK 3
#define MAXZ 100
#define CUTOFF 6.0f
#define PI_F 3.14159265358979323846f
#define ETILE 64
#define TABN 2048                        // table intervals over [0, CUTOFF]

typedef unsigned short ushort_t;
typedef unsigned char uchar_t;
typedef unsigned long long ull_t;
typedef __attribute__((ext_vector_type(8))) short short8;
typedef __attribute__((ext_vector_type(4))) float f32x4;

__device__ __forceinline__ float fexp2(float x) {
    float r; asm("v_exp_f32 %0, %1" : "=v"(r) : "v"(x)); return r;
}
__device__ __forceinline__ float frcp(float x) {
    float r; asm("v_rcp_f32 %0, %1" : "=v"(r) : "v"(x)); return r;
}
// silu(x) = x / (1 + exp(-x)) = x * rcp(1 + 2^(-x*log2e))
__device__ __forceinline__ float silu(float x) {
    return x * frcp(1.0f + fexp2(x * -1.44269504f));
}

__device__ __forceinline__ ushort_t f2bf(float v) {          // fast RNE (finite inputs)
    unsigned int u = __float_as_uint(v);
    return (ushort_t)((u + 0x7FFF + ((u >> 16) & 1)) >> 16);
}
__device__ __forceinline__ float bf2f(ushort_t u) {
    return __uint_as_float((unsigned int)u << 16);
}

__device__ __forceinline__ f32x4 MFMA(short8 a, short8 b, f32x4 c) {
    return __builtin_amdgcn_mfma_f32_16x16x32_bf16(a, b, c, 0, 0, 0);
}

// swizzled byte offset for [64][128] bf16 LDS tiles: (row*256 + col*2) ^ ((row&7)<<4)
__device__ __forceinline__ int swz(int row, int k) {
    return (row * 256 + k * 2) ^ ((row & 7) << 4);
}

__device__ __forceinline__ short8 ldB(const ushort_t* W, int col, int K, int k) {
    return *reinterpret_cast<const short8*>(W + (size_t)col * K + k);
}

// ---- fused zero-init: out force region, agg, cnt ----
__global__ void k_init(float* __restrict__ out, float* __restrict__ agg,
                       int* __restrict__ cnt) {
    int i = blockIdx.x * blockDim.x + threadIdx.x;
    if (i < N_ATOMS * 3) out[i] = 0.0f;
    if (i < N_ATOMS) cnt[i] = 0;
    if (i < NBLOCK * N_ATOMS * HID) agg[i] = 0.0f;
}

// ---- counting sort of edges by dst ----
__global__ void k_hist(const int* __restrict__ edge_index, int* __restrict__ cnt) {
    int e = blockIdx.x * blockDim.x + threadIdx.x;
    if (e < N_EDGES) atomicAdd(&cnt[edge_index[N_EDGES + e]], 1);
}

__global__ void k_scan(const int* __restrict__ cnt, int* __restrict__ cursor) {
    __shared__ int partial[256];
    int t = threadIdx.x;
    int base = t * (N_ATOMS / 256);
    int s = 0;
    for (int j = 0; j < N_ATOMS / 256; j++) s += cnt[base + j];
    partial[t] = s;
    __syncthreads();
    if (t == 0) {
        int run = 0;
        for (int i = 0; i < 256; i++) { int v = partial[i]; partial[i] = run; run += v; }
    }
    __syncthreads();
    int run = partial[t];
    for (int j = 0; j < N_ATOMS / 256; j++) {
        cursor[base + j] = run;
        run += cnt[base + j];
    }
}

__global__ void k_scatter(const int* __restrict__ edge_index,
                          int* __restrict__ cursor, int* __restrict__ perm) {
    int e = blockIdx.x * blockDim.x + threadIdx.x;
    if (e < N_EDGES) {
        int pos = atomicAdd(&cursor[edge_index[N_EDGES + e]], 1);
        perm[pos] = e;
    }
}

// ---- lattice matrices ----
__global__ void k_latt(const float* __restrict__ lengths,
                       const float* __restrict__ angles,
                       float* __restrict__ latt) {
    int c = blockIdx.x * blockDim.x + threadIdx.x;
    if (c >= N_CRYST) return;
    float a  = lengths[c * 3 + 0];
    float b  = lengths[c * 3 + 1];
    float cc = lengths[c * 3 + 2];
    float al = angles[c * 3 + 0] * (PI_F / 180.0f);
    float be = angles[c * 3 + 1] * (PI_F / 180.0f);
    float ga = angles[c * 3 + 2] * (PI_F / 180.0f);
    float cos_a = cosf(al), cos_b = cosf(be), cos_g = cosf(ga);
    float sin_a = sinf(al), sin_b = sinf(be);
    float val = (cos_a * cos_b - cos_g) / (sin_a * sin_b);
    val = fminf(1.0f, fmaxf(-1.0f, val));
    float gs = acosf(val);
    float* L = latt + c * 9;
    L[0] = a * sin_b;              L[1] = 0.0f;                  L[2] = a * cos_b;
    L[3] = -b * sin_a * cosf(gs);  L[4] = b * sin_a * sinf(gs);  L[5] = b * cos_a;
    L[6] = 0.0f;                   L[7] = 0.0f;                  L[8] = cc;
}

// ---- cartesian coords ----
__global__ void k_cart(const float* __restrict__ frac,
                       const float* __restrict__ latt,
                       float* __restrict__ cart) {
    int n = blockIdx.x * blockDim.x + threadIdx.x;
    if (n >= N_ATOMS) return;
    int b = n / ATOMS_PER;
    const float* L = latt + b * 9;
    float f0 = frac[n * 3 + 0], f1 = frac[n * 3 + 1], f2 = frac[n * 3 + 2];
    cart[n * 3 + 0] = f0 * L[0] + f1 * L[3] + f2 * L[6];
    cart[n * 3 + 1] = f0 * L[1] + f1 * L[4] + f2 * L[7];
    cart[n * 3 + 2] = f0 * L[2] + f1 * L[5] + f2 * L[8];
}

// ---- rbf_h lookup table: T[j][c] = sum_k rbf_k(d_j) * W_rbf[k][c] ----
__global__ void k_tab(const float* __restrict__ W_rbf, float* __restrict__ T) {
    int j = blockIdx.x;       // 0..TABN+1
    int c = threadIdx.x;      // 0..127
    __shared__ float rbf[NRAD];
    float d = (float)j * (CUTOFF / TABN);
    const float inv2w2 = 1.0f / (2.0f * (CUTOFF / NRAD) * (CUTOFF / NRAD));
    const float cstep = CUTOFF / (NRAD - 1);
    float x = fminf(1.0f, d * (1.0f / CUTOFF));
    float env = 0.5f * (cosf(PI_F * x) + 1.0f);
    float diff = d - (float)c * cstep;
    rbf[c] = expf(-diff * diff * inv2w2) * env;
    __syncthreads();
    float acc = 0.0f;
#pragma unroll 8
    for (int k = 0; k < NRAD; k++) acc += rbf[k] * W_rbf[k * HID + c];
    T[j * HID + c] = acc;
}

// ---- weight prep: transpose + bf16 (Wt[col][k], k contiguous = B-fragment layout) ----
__global__ void k_prep(const float* __restrict__ W_edge,
                       const float* __restrict__ W_msg,
                       const float* __restrict__ W_gate,
                       const float* __restrict__ W_upd,
                       const float* __restrict__ W_atom,
                       ushort_t* __restrict__ Wt_edge,
                       ushort_t* __restrict__ Wt_msg,
                       ushort_t* __restrict__ Wt_gate,
                       ushort_t* __restrict__ Wt_upd,
                       ushort_t* __restrict__ Wt_atom) {
    int i = blockIdx.x * blockDim.x + threadIdx.x;
    if (i < 128 * 384) {
        int c = i / 384, k = i % 384;
        Wt_edge[(size_t)c * 384 + k] = f2bf(W_edge[k * 128 + c]);
    }
    if (i < 3 * 128 * 128) {
        int blk = i >> 14, r = i & 16383;
        int c = r >> 7, k = r & 127;
        Wt_msg[blk * 16384 + c * 128 + k]  = f2bf(W_msg[blk * 16384 + k * 128 + c]);
        Wt_gate[blk * 16384 + c * 128 + k] = f2bf(W_gate[blk * 16384 + k * 128 + c]);
        Wt_upd[blk * 16384 + c * 128 + k]  = f2bf(W_upd[blk * 16384 + k * 128 + c]);
    }
    if (i < 128 * 128) {
        int c = i >> 7, k = i & 127;
        Wt_atom[c * 128 + k] = (c < MAXZ) ? f2bf(W_atom[k * MAXZ + c]) : (ushort_t)0;
    }
}

// ---- h0 path (split): h0[n] = silu(embW[type[n]] + zW[batch[n]]) ----
__global__ void k_embW(const float* __restrict__ atom_emb,
                       const float* __restrict__ W_in,
                       const float* __restrict__ b_in,
                       float* __restrict__ embW) {
    int zi = blockIdx.x;
    int c = threadIdx.x;
    __shared__ float row[HID];
    row[c] = atom_emb[zi * HID + c];
    __syncthreads();
    float acc = b_in[c];
#pragma unroll 8
    for (int k = 0; k < HID; k++) acc += row[k] * W_in[k * HID + c];
    embW[zi * HID + c] = acc;
}

__global__ void k_zW(const float* __restrict__ z,
                     const float* __restrict__ W_in,
                     float* __restrict__ zW) {
    int b = blockIdx.x;
    int c = threadIdx.x;
    __shared__ float row[LAT];
    row[c]       = z[b * LAT + c];
    row[128 + c] = z[b * LAT + 128 + c];
    __syncthreads();
    float acc = 0.f;
#pragma unroll 8
    for (int k = 0; k < LAT; k++) acc += row[k] * W_in[(HID + k) * HID + c];
    zW[b * HID + c] = acc;
}

__global__ void k_h2(const int* __restrict__ types,
                     const float* __restrict__ embW,
                     const float* __restrict__ zW,
                     ushort_t* __restrict__ h_bf) {
    int idx = blockIdx.x * 256 + threadIdx.x;
    int n = idx >> 7, c = idx & 127;
    float v = embW[types[n] * HID + c] + zW[(n >> 6) * HID + c];
    h_bf[idx] = f2bf(silu(v));
}

// ---- Fused edge kernel: staged-h all-LDS GEMMs, M2T-overlays-HD, MFMA segment-sum ----
__global__ __launch_bounds__(512, 6)
void k_edges(const int* __restrict__ perm,
             const int* __restrict__ edge_index,
             const float* __restrict__ cart,
             const float* __restrict__ T,      // [TABN+2][HID] rbf_h table
             const ushort_t* __restrict__ h_bf,
             const ushort_t* __restrict__ Wt_edge,
             const float* __restrict__ b_edge,
             const ushort_t* __restrict__ Wt_msg,
             const float* __restrict__ b_msg,
             const ushort_t* __restrict__ Wt_gate,
             const float* __restrict__ W_force,
             float* __restrict__ agg,    // [NBLOCK][N_ATOMS][HID]
             float* __restrict__ outF)   // [N_ATOMS][3]
{
    __shared__ ushort_t R2[ETILE * HID];    // rbf_h (persists)
    __shared__ ushort_t HSR3[ETILE * HID];  // staged h_src, then running m
    __shared__ ushort_t HD[ETILE * HID];    // staged h_dst, then M2T (m2 transposed)
    __shared__ int   sm_dst[ETILE];
    __shared__ float sm_unit[ETILE][3];
    __shared__ float sm_d[ETILE];
    __shared__ float sm_f[ETILE];
    __shared__ uchar_t sm_runid8[ETILE];
    __shared__ int   sm_slotdst[ETILE];
    __shared__ int   sm_nruns;
    ushort_t* M2T = HD;    // HD is dead after GEMM2 (barrier B3a/B3b)

    const int t    = threadIdx.x;
    const int lane = t & 63;
    const int wave = t >> 6;             // 0..7
    const int l15  = lane & 15;
    const int g4   = lane >> 4;          // 0..3
    const int lk8  = 8 * g4;
    const int colw = wave * 16;          // this wave's 16 output cols
    const int e0   = blockIdx.x * ETILE;

    // per-lane static LDS addressing bases
    const int laneA = l15 * 256 + ((lk8 * 2) ^ ((l15 & 7) << 4));   // A-frag read base
    const int colM  = colw + l15;                                    // this lane's col
    int woff[4];                                                     // R3 C-write bases
#pragma unroll
    for (int r = 0; r < 4; r++) {
        int row = g4 * 4 + r;
        woff[r] = row * 256 + ((colM * 2) ^ ((row & 7) << 4));
    }

    // ---- T14: issue h_src/h_dst tile loads EARLY (coalesced per 16-thread row) ----
    short8 hs[2], hd[2];
    int stoff[2];
#pragma unroll
    for (int p = 0; p < 2; p++) {
        int u   = p * 512 + t;       // 0..1023 = 64 rows x 16 chunks
        int row = u >> 4;
        int seg = u & 15;
        int eid = perm[e0 + row];
        int s = edge_index[eid];
        int d = edge_index[N_EDGES + eid];
        hs[p] = *reinterpret_cast<const short8*>(h_bf + (size_t)s * HID + seg * 8);
        hd[p] = *reinterpret_cast<const short8*>(h_bf + (size_t)d * HID + seg * 8);
        stoff[p] = swz(row, seg * 8);
    }

    // ---- Phase A: geometry ----
    if (t < ETILE) {
        int e = t;
        int eid = perm[e0 + e];
        int s = edge_index[eid];
        int d = edge_index[N_EDGES + eid];
        sm_dst[e] = d;
        float vx = cart[d * 3 + 0] - cart[s * 3 + 0];
        float vy = cart[d * 3 + 1] - cart[s * 3 + 1];
        float vz = cart[d * 3 + 2] - cart[s * 3 + 2];
        float dist = sqrtf(vx * vx + vy * vy + vz * vz) + 1e-8f;
        sm_d[e] = dist;
        float di = 1.0f / dist;
        sm_unit[e][0] = vx * di; sm_unit[e][1] = vy * di; sm_unit[e][2] = vz * di;
        sm_f[e] = 0.0f;
    }
    __syncthreads();   // B1

    // ---- run ids over sorted dst (wave 0, ballot) ----
    if (wave == 0) {
        int e = lane;
        int d = sm_dst[e];
        int prev = (e == 0) ? -1 : sm_dst[e - 1];
        ull_t mask = __ballot(d != prev);
        int rid = __popcll(mask & ((2ull << e) - 1)) - 1;
        sm_runid8[e] = (uchar_t)rid;
        if (d != prev) sm_slotdst[rid] = d;
        if (e == 0) sm_nruns = __popcll(mask);
    }

    // ---- Phase B: rbf_h via table lerp -> R2 ; write staged h tiles ----
    {
#pragma unroll
        for (int it = 0; it < 4; it++) {
            int u = it * 512 + t;          // 2048 units = 64 edges x 32 col-quads
            int e = u >> 5;
            int p = u & 31;                // cols 4p..4p+3
            float idxf = sm_d[e] * (TABN / CUTOFF);
            idxf = fminf(idxf, (float)TABN);
            int j = (int)idxf;
            float fr = idxf - (float)j;
            f32x4 lo = *reinterpret_cast<const f32x4*>(T + (size_t)j * HID + 4 * p);
            f32x4 hi = *reinterpret_cast<const f32x4*>(T + (size_t)(j + 1) * HID + 4 * p);
            unsigned int pk0, pk1;
            {
                float v0 = lo[0] + fr * (hi[0] - lo[0]);
                float v1 = lo[1] + fr * (hi[1] - lo[1]);
                float v2 = lo[2] + fr * (hi[2] - lo[2]);
                float v3 = lo[3] + fr * (hi[3] - lo[3]);
                pk0 = ((unsigned int)f2bf(v1) << 16) | f2bf(v0);
                pk1 = ((unsigned int)f2bf(v3) << 16) | f2bf(v2);
            }
            int off = (e * 256 + 8 * p) ^ ((e & 7) << 4);
            *reinterpret_cast<unsigned int*>(reinterpret_cast<char*>(R2) + off)     = pk0;
            *reinterpret_cast<unsigned int*>(reinterpret_cast<char*>(R2) + off + 4) = pk1;
        }
        // staged h -> LDS (vmcnt waits inserted by compiler)
#pragma unroll
        for (int p = 0; p < 2; p++) {
            *reinterpret_cast<short8*>(reinterpret_cast<char*>(HSR3) + stoff[p]) = hs[p];
            *reinterpret_cast<short8*>(reinterpret_cast<char*>(HD)   + stoff[p]) = hd[p];
        }
    }
    __syncthreads();   // B2

    // ---- GEMM2 (all-LDS A): m0 = silu([h_src|h_dst|rbf_h] @ W_edge + b_edge) ----
    float m_acc[4][4];     // [at][r]
    {
        f32x4 am[4];
#pragma unroll
        for (int at = 0; at < 4; at++) am[at] = (f32x4){0.f, 0.f, 0.f, 0.f};
        const ushort_t* segp[3] = {HSR3, HD, R2};
#pragma unroll
        for (int seg = 0; seg < 3; seg++) {
#pragma unroll
            for (int ks = 0; ks < 4; ks++) {
                int kg = seg * 128 + ks * 32 + lk8;
                short8 B0 = ldB(Wt_edge, colM, 384, kg);
                int lA = laneA ^ (ks * 64);
#pragma unroll
                for (int at = 0; at < 4; at++) {
                    short8 A = *reinterpret_cast<const short8*>(
                        reinterpret_cast<const char*>(segp[seg]) + (lA + at * 4096));
                    am[at] = MFMA(A, B0, am[at]);
                }
            }
        }
        float be0 = b_edge[colM];
#pragma unroll
        for (int at = 0; at < 4; at++)
#pragma unroll
            for (int r = 0; r < 4; r++)
                m_acc[at][r] = silu(am[at][r] + be0);
    }
    __syncthreads();   // B3a: all HSR3/HD reads complete

    // publish m -> HSR3 (now R3)
#pragma unroll
    for (int at = 0; at < 4; at++)
#pragma unroll
        for (int r = 0; r < 4; r++)
            *reinterpret_cast<ushort_t*>(reinterpret_cast<char*>(HSR3) +
                (woff[r] + at * 4096)) = f2bf(m_acc[at][r]);
    __syncthreads();   // B3b

    // ---- message blocks ----
    for (int i = 0; i < NBLOCK; i++) {
        const ushort_t* Wm = Wt_msg  + i * 16384;
        const ushort_t* Wg = Wt_gate + i * 16384;
        float* aggp = agg + (size_t)i * N_ATOMS * HID;
        // P1: msg + gate GEMMs; epilogue -> M2T (transposed, b64-packed)
        {
            float bm = b_msg[i * HID + colM];
            f32x4 am_[4], ag_[4];
#pragma unroll
            for (int at = 0; at < 4; at++) {
                am_[at] = (f32x4){0.f, 0.f, 0.f, 0.f};
                ag_[at] = (f32x4){0.f, 0.f, 0.f, 0.f};
            }
#pragma unroll
            for (int ks = 0; ks < 4; ks++) {
                short8 Bm = ldB(Wm, colM, 128, ks * 32 + lk8);
                short8 Bg = ldB(Wg, colM, 128, ks * 32 + lk8);
                int lA = laneA ^ (ks * 64);
#pragma unroll
                for (int at = 0; at < 4; at++) {
                    short8 Am = *reinterpret_cast<const short8*>(
                        reinterpret_cast<const char*>(HSR3) + (lA + at * 4096));
                    short8 Ag = *reinterpret_cast<const short8*>(
                        reinterpret_cast<const char*>(R2) + (lA + at * 4096));
                    am_[at] = MFMA(Am, Bm, am_[at]);
                    ag_[at] = MFMA(Ag, Bg, ag_[at]);
                }
            }
#pragma unroll
            for (int at = 0; at < 4; at++) {
                float m2v[4];
#pragma unroll
                for (int r = 0; r < 4; r++) {
                    float m2 = silu(am_[at][r] + bm) * ag_[at][r];
                    m2v[r] = m2;
                    m_acc[at][r] += m2;
                }
                unsigned int plo = ((unsigned int)f2bf(m2v[1]) << 16) | f2bf(m2v[0]);
                unsigned int phi = ((unsigned int)f2bf(m2v[3]) << 16) | f2bf(m2v[2]);
                ull_t pk = ((ull_t)phi << 32) | plo;
                int addr = (colM * 128 + (at * 16 + g4 * 4) * 2) ^ ((colM & 7) << 4);
                *reinterpret_cast<ull_t*>(reinterpret_cast<char*>(M2T) + addr) = pk;
            }
        }
        __syncthreads();   // Ba: M2T complete; all R3/R2 reads done

        // P2: segment sum via MFMA: agg[run][c] = sum_e S[run][e] * m2[e][c]
        {
            int nruns = sm_nruns;
            short8 Bm2[2];
#pragma unroll
            for (int ks = 0; ks < 2; ks++) {
                int addr = (colM * 128 + (ks * 32 + lk8) * 2) ^ ((colM & 7) << 4);
                Bm2[ks] = *reinterpret_cast<const short8*>(
                    reinterpret_cast<const char*>(M2T) + addr);
            }
            for (int rt = 0; rt * 16 < nruns; rt++) {
                int tv = l15 + rt * 16;       // run this lane's A-row represents
                short8 SA[2];
#pragma unroll
                for (int ks = 0; ks < 2; ks++) {
                    ull_t rid8 = *reinterpret_cast<const ull_t*>(sm_runid8 + ks * 32 + lk8);
                    unsigned int rlo = (unsigned int)rid8;
                    unsigned int rhi = (unsigned int)(rid8 >> 32);
                    union { unsigned int u[4]; short8 s8; } sb;
#pragma unroll
                    for (int q = 0; q < 2; q++) {
                        unsigned int rr = q ? rhi : rlo;
                        unsigned int w0 = 0, w1 = 0;
                        if ((int)((rr >>  0) & 255) == tv) w0 |= 0x3F80u;
                        if ((int)((rr >>  8) & 255) == tv) w0 |= 0x3F800000u;
                        if ((int)((rr >> 16) & 255) == tv) w1 |= 0x3F80u;
                        if ((int)((rr >> 24) & 255) == tv) w1 |= 0x3F800000u;
                        sb.u[q * 2]     = w0;
                        sb.u[q * 2 + 1] = w1;
                    }
                    SA[ks] = sb.s8;
                }
                f32x4 acc0 = {0.f, 0.f, 0.f, 0.f};
                acc0 = MFMA(SA[0], Bm2[0], acc0);
                acc0 = MFMA(SA[1], Bm2[1], acc0);
#pragma unroll
                for (int r = 0; r < 4; r++) {
                    int run = rt * 16 + g4 * 4 + r;
                    if (run < nruns) {
                        int d = sm_slotdst[run];
                        atomicAdd(&aggp[(size_t)d * HID + colM], acc0[r]);
                    }
                }
            }
        }

        // publish updated m (R3; reads of old R3 finished at Ba)
        if (i < NBLOCK - 1) {
#pragma unroll
            for (int at = 0; at < 4; at++)
#pragma unroll
                for (int r = 0; r < 4; r++)
                    *reinterpret_cast<ushort_t*>(reinterpret_cast<char*>(HSR3) +
                        (woff[r] + at * 4096)) = f2bf(m_acc[at][r]);
        }
        __syncthreads();   // Bb: R3 ready, M2T free
    }

    // ---- force: f_e = m . W_force ; run-aggregated outF[dst] += f_e * unit ----
    {
        float wf0 = W_force[colM];
#pragma unroll
        for (int at = 0; at < 4; at++)
#pragma unroll
            for (int r = 0; r < 4; r++) {
                float part = m_acc[at][r] * wf0;
                part += __shfl_xor(part, 1, 64);
                part += __shfl_xor(part, 2, 64);
                part += __shfl_xor(part, 4, 64);
                part += __shfl_xor(part, 8, 64);
                if (l15 == 0)
                    atomicAdd(&sm_f[at * 16 + g4 * 4 + r], part);
            }
        __syncthreads();
        if (t < ETILE) {
            int e = t;
            int d = sm_dst[e];
            if (e == 0 || sm_dst[e - 1] != d) {
                float fx = 0.f, fy = 0.f, fz = 0.f;
                int j = e;
                do {
                    float f = sm_f[j];
                    fx += f * sm_unit[j][0];
                    fy += f * sm_unit[j][1];
                    fz += f * sm_unit[j][2];
                    j++;
                } while (j < ETILE && sm_dst[j] == d);
                atomicAdd(&outF[d * 3 + 0], fx);
                atomicAdd(&outF[d * 3 + 1], fy);
                atomicAdd(&outF[d * 3 + 2], fz);
            }
        }
    }
}

// ---- Atom-side (MFMA): h = h0 + sum_i silu(agg_i @ W_upd_i + b); out = h @ W_atom + b ----
__global__ __launch_bounds__(256)
void k_atom2(const float* __restrict__ agg,
             const ushort_t* __restrict__ Wt_upd,    // [3][128 col][128 k]
             const float* __restrict__ b_upd,
             const ushort_t* __restrict__ Wt_atom,   // [128 col(pad)][128 k]
             const float* __restrict__ b_atom,
             const ushort_t* __restrict__ h_bf,
             float* __restrict__ out) {
    __shared__ ushort_t RA[64 * HID];   // 16 KB staged A tile

    const int t    = threadIdx.x;
    const int lane = t & 63;
    const int wave = t >> 6;
    const int l15  = lane & 15;
    const int lk8  = 8 * (lane >> 4);
    const int colw = wave * 32;
    const int n0   = blockIdx.x * 64;

    const int laneA = l15 * 256 + ((lk8 * 2) ^ ((l15 & 7) << 4));
    int woff[2][4];
#pragma unroll
    for (int nt = 0; nt < 2; nt++)
#pragma unroll
        for (int r = 0; r < 4; r++) {
            int row = (lane >> 4) * 4 + r;
            woff[nt][r] = row * 256 + (((colw + nt * 16 + l15) * 2) ^ ((row & 7) << 4));
        }

    // h0 in C-layout f32 regs
    float h_acc[4][2][4];
#pragma unroll
    for (int at = 0; at < 4; at++)
#pragma unroll
        for (int nt = 0; nt < 2; nt++)
#pragma unroll
            for (int r = 0; r < 4; r++) {
                int row = at * 16 + (lane >> 4) * 4 + r;
                h_acc[at][nt][r] = bf2f(h_bf[(size_t)(n0 + row) * HID + colw + nt * 16 + l15]);
            }

    for (int i = 0; i < NBLOCK; i++) {
        // stage agg_i tile -> RA (f32 -> bf16, swizzled); coalesced f32x4 loads
        const float* ap = agg + (size_t)i * N_ATOMS * HID + (size_t)n0 * HID;
#pragma unroll
        for (int it = 0; it < 8; it++) {
            int u = it * 256 + t;
            int row = u >> 5, p = u & 31;
            f32x4 v = *reinterpret_cast<const f32x4*>(ap + (size_t)row * HID + 4 * p);
            unsigned int pk0 = ((unsigned int)f2bf(v[1]) << 16) | f2bf(v[0]);
            unsigned int pk1 = ((unsigned int)f2bf(v[3]) << 16) | f2bf(v[2]);
            int off = (row * 256 + 8 * p) ^ ((row & 7) << 4);
            *reinterpret_cast<unsigned int*>(reinterpret_cast<char*>(RA) + off)     = pk0;
            *reinterpret_cast<unsigned int*>(reinterpret_cast<char*>(RA) + off + 4) = pk1;
        }
        __syncthreads();

        const ushort_t* Wu = Wt_upd + i * 16384;
        float bu0 = b_upd[i * HID + colw + l15];
        float bu1 = b_upd[i * HID + colw + 16 + l15];
        f32x4 am[4][2];
#pragma unroll
        for (int at = 0; at < 4; at++)
#pragma unroll
            for (int nt = 0; nt < 2; nt++)
                am[at][nt] = (f32x4){0.f, 0.f, 0.f, 0.f};
#pragma unroll
        for (int ks = 0; ks < 4; ks++) {
            short8 B0 = ldB(Wu, colw + l15,      128, ks * 32 + lk8);
            short8 B1 = ldB(Wu, colw + 16 + l15, 128, ks * 32 + lk8);
            int lA = laneA ^ (ks * 64);
#pragma unroll
            for (int at = 0; at < 4; at++) {
                short8 A = *reinterpret_cast<const short8*>(
                    reinterpret_cast<const char*>(RA) + (lA + at * 4096));
                am[at][0] = MFMA(A, B0, am[at][0]);
                am[at][1] = MFMA(A, B1, am[at][1]);
            }
        }
#pragma unroll
        for (int at = 0; at < 4; at++)
#pragma unroll
            for (int r = 0; r < 4; r++) {
                h_acc[at][0][r] += silu(am[at][0][r] + bu0);
                h_acc[at][1][r] += silu(am[at][1][r] + bu1);
            }
        __syncthreads();
    }

    // publish h -> RA (bf16), head GEMM
#pragma unroll
    for (int at = 0; at < 4; at++)
#pragma unroll
        for (int nt = 0; nt < 2; nt++)
#pragma unroll
            for (int r = 0; r < 4; r++)
                *reinterpret_cast<ushort_t*>(reinterpret_cast<char*>(RA) +
                    (woff[nt][r] + at * 4096)) = f2bf(h_acc[at][nt][r]);
    __syncthreads();

    {
        f32x4 am[4][2];
#pragma unroll
        for (int at = 0; at < 4; at++)
#pragma unroll
            for (int nt = 0; nt < 2; nt++)
                am[at][nt] = (f32x4){0.f, 0.f, 0.f, 0.f};
#pragma unroll
        for (int ks = 0; ks < 4; ks++) {
            short8 B0 = ldB(Wt_atom, colw + l15,      128, ks * 32 + lk8);
            short8 B1 = ldB(Wt_atom, colw + 16 + l15, 128, ks * 32 + lk8);
            int lA = laneA ^ (ks * 64);
#pragma unroll
            for (int at = 0; at < 4; at++) {
                short8 A = *reinterpret_cast<const short8*>(
                    reinterpret_cast<const char*>(RA) + (lA + at * 4096));
                am[at][0] = MFMA(A, B0, am[at][0]);
                am[at][1] = MFMA(A, B1, am[at][1]);
            }
        }
        int col0 = colw + l15;
        int col1 = colw + 16 + l15;
        float ba0 = (col0 < MAXZ) ? b_atom[col0] : 0.f;
        float ba1 = (col1 < MAXZ) ? b_atom[col1] : 0.f;
#pragma unroll
        for (int at = 0; at < 4; at++)
#pragma unroll
            for (int r = 0; r < 4; r++) {
                int row = n0 + at * 16 + (lane >> 4) * 4 + r;
                if (col0 < MAXZ)
                    out[(size_t)N_ATOMS * 3 + (size_t)row * MAXZ + col0] = am[at][0][r] + ba0;
                if (col1 < MAXZ)
                    out[(size_t)N_ATOMS * 3 + (size_t)row * MAXZ + col1] = am[at][1][r] + ba1;
            }
    }
}

extern "C" void kernel_launch(void* const* d_in, const int* in_sizes, int n_in,
                              void* d_out, int out_size, void* d_ws, size_t ws_size,
                              hipStream_t stream) {
    const float* z         = (const float*)d_in[0];
    const float* frac      = (const float*)d_in[1];
    const int*   types     = (const int*)d_in[2];
    const float* lengths   = (const float*)d_in[4];
    const float* angles    = (const float*)d_in[5];
    const int*   edge_idx  = (const int*)d_in[6];
    const float* atom_emb  = (const float*)d_in[7];
    const float* W_in      = (const float*)d_in[8];
    const float* b_in      = (const float*)d_in[9];
    const float* W_rbf     = (const float*)d_in[10];
    const float* W_edge    = (const float*)d_in[11];
    const float* b_edge    = (const float*)d_in[12];
    const float* W_msg     = (const float*)d_in[13];
    const float* b_msg     = (const float*)d_in[14];
    const float* W_gate    = (const float*)d_in[15];
    const float* W_upd     = (const float*)d_in[16];
    const float* b_upd     = (const float*)d_in[17];
    const float* W_force   = (const float*)d_in[18];
    const float* W_atom    = (const float*)d_in[19];
    const float* b_atom    = (const float*)d_in[20];

    float* out = (float*)d_out;

    // workspace layout
    float* ws = (float*)d_ws;
    size_t off = 0;
    float* latt = ws + off; off += N_CRYST * 9;
    float* cart = ws + off; off += (size_t)N_ATOMS * 3;
    float* agg  = ws + off; off += (size_t)NBLOCK * N_ATOMS * HID;
    float* embW = ws + off; off += MAXZ * HID;
    float* zW   = ws + off; off += N_CRYST * HID;
    float* T    = ws + off; off += (size_t)(TABN + 2) * HID;
    int* cnt    = (int*)(ws + off); off += N_ATOMS;
    int* cursor = (int*)(ws + off); off += N_ATOMS;
    int* perm   = (int*)(ws + off); off += N_EDGES;
    off = (off + 7) & ~(size_t)7;
    ushort_t* ub = (ushort_t*)(ws + off);
    size_t uoff = 0;
    ushort_t* h_bf    = ub + uoff; uoff += (size_t)N_ATOMS * HID;
    ushort_t* Wt_edge = ub + uoff; uoff += 128 * 384;
    ushort_t* Wt_msg  = ub + uoff; uoff += 3 * 128 * 128;
    ushort_t* Wt_gate = ub + uoff; uoff += 3 * 128 * 128;
    ushort_t* Wt_upd  = ub + uoff; uoff += 3 * 128 * 128;
    ushort_t* Wt_atom = ub + uoff; uoff += 128 * 128;

    // fused zero-init (out force region, agg, cnt)
    k_init<<<(NBLOCK * N_ATOMS * HID + 255) / 256, 256, 0, stream>>>(out, agg, cnt);

    // counting sort by dst
    k_hist<<<(N_EDGES + 255) / 256, 256, 0, stream>>>(edge_idx, cnt);
    k_scan<<<1, 256, 0, stream>>>(cnt, cursor);
    k_scatter<<<(N_EDGES + 255) / 256, 256, 0, stream>>>(edge_idx, cursor, perm);

    k_latt<<<1, 256, 0, stream>>>(lengths, angles, latt);
    k_cart<<<(N_ATOMS + 255) / 256, 256, 0, stream>>>(frac, latt, cart);
    k_tab<<<TABN + 2, HID, 0, stream>>>(W_rbf, T);
    k_prep<<<192, 256, 0, stream>>>(W_edge, W_msg, W_gate, W_upd, W_atom,
                                    Wt_edge, Wt_msg, Wt_gate, Wt_upd, Wt_atom);

    // h0 path
    k_embW<<<MAXZ, HID, 0, stream>>>(atom_emb, W_in, b_in, embW);
    k_zW<<<N_CRYST, HID, 0, stream>>>(z, W_in, zW);
    k_h2<<<(N_ATOMS * HID) / 256, 256, 0, stream>>>(types, embW, zW, h_bf);

    k_edges<<<N_EDGES / ETILE, 512, 0, stream>>>(perm, edge_idx, cart, T, h_bf,
                                                 Wt_edge, b_edge,
                                                 Wt_msg, b_msg, Wt_gate, W_force,
                                                 agg, out);

    k_atom2<<<N_ATOMS / 64, 256, 0, stream>>>(agg, Wt_upd, b_upd, Wt_atom, b_atom,
                                              h_bf, out);
}

// Round 12
// 393.464 us; speedup vs baseline: 1.1443x; 1.1443x over previous
//
#include <hip/hip_runtime.h>
#include <hip/hip_bf16.h>

#define N_CRYST 256
#define ATOMS_PER 64
#define N_ATOMS (N_CRYST * ATOMS_PER)   // 16384
#define N_EDGES (N_ATOMS * 20)          // 327680
#define HID 128
#define LAT 256
#define NRAD 128
#define NBLOCK 3
#define MAXZ 100
#define CUTOFF 6.0f
#define PI_F 3.14159265358979323846f
#define ETILE 64
#define TABN 2048                        // table intervals over [0, CUTOFF]

typedef unsigned short ushort_t;
typedef unsigned char uchar_t;
typedef unsigned long long ull_t;
typedef __attribute__((ext_vector_type(8))) short short8;
typedef __attribute__((ext_vector_type(4))) float f32x4;

__device__ __forceinline__ float fexp2(float x) {
    float r; asm("v_exp_f32 %0, %1" : "=v"(r) : "v"(x)); return r;
}
__device__ __forceinline__ float frcp(float x) {
    float r; asm("v_rcp_f32 %0, %1" : "=v"(r) : "v"(x)); return r;
}
// silu(x) = x / (1 + exp(-x)) = x * rcp(1 + 2^(-x*log2e))
__device__ __forceinline__ float silu(float x) {
    return x * frcp(1.0f + fexp2(x * -1.44269504f));
}

__device__ __forceinline__ ushort_t f2bf(float v) {          // fast RNE (finite inputs)
    unsigned int u = __float_as_uint(v);
    return (ushort_t)((u + 0x7FFF + ((u >> 16) & 1)) >> 16);
}
__device__ __forceinline__ float bf2f(ushort_t u) {
    return __uint_as_float((unsigned int)u << 16);
}
// packed bf16 convert: dst.lo = bf16(lo), dst.hi = bf16(hi) — 1 VALU instr
__device__ __forceinline__ unsigned int pkbf(float lo, float hi) {
    unsigned int r;
    asm("v_cvt_pk_bf16_f32 %0, %1, %2" : "=v"(r) : "v"(lo), "v"(hi));
    return r;
}

__device__ __forceinline__ f32x4 MFMA(short8 a, short8 b, f32x4 c) {
    return __builtin_amdgcn_mfma_f32_16x16x32_bf16(a, b, c, 0, 0, 0);
}

// swizzled byte offset for [64][128] bf16 LDS tiles: (row*256 + col*2) ^ ((row&7)<<4)
__device__ __forceinline__ int swz(int row, int k) {
    return (row * 256 + k * 2) ^ ((row & 7) << 4);
}

__device__ __forceinline__ short8 ldB(const ushort_t* W, int col, int K, int k) {
    return *reinterpret_cast<const short8*>(W + (size_t)col * K + k);
}

// ---- fused zero-init: out force region, agg, cnt ----
__global__ void k_init(float* __restrict__ out, float* __restrict__ agg,
                       int* __restrict__ cnt) {
    int i = blockIdx.x * blockDim.x + threadIdx.x;
    if (i < N_ATOMS * 3) out[i] = 0.0f;
    if (i < N_ATOMS) cnt[i] = 0;
    if (i < NBLOCK * N_ATOMS * HID) agg[i] = 0.0f;
}

// ---- counting sort of edges by dst ----
__global__ void k_hist(const int* __restrict__ edge_index, int* __restrict__ cnt) {
    int e = blockIdx.x * blockDim.x + threadIdx.x;
    if (e < N_EDGES) atomicAdd(&cnt[edge_index[N_EDGES + e]], 1);
}

__global__ void k_scan(const int* __restrict__ cnt, int* __restrict__ cursor) {
    __shared__ int partial[256];
    int t = threadIdx.x;
    int base = t * (N_ATOMS / 256);
    int s = 0;
    for (int j = 0; j < N_ATOMS / 256; j++) s += cnt[base + j];
    partial[t] = s;
    __syncthreads();
    if (t == 0) {
        int run = 0;
        for (int i = 0; i < 256; i++) { int v = partial[i]; partial[i] = run; run += v; }
    }
    __syncthreads();
    int run = partial[t];
    for (int j = 0; j < N_ATOMS / 256; j++) {
        cursor[base + j] = run;
        run += cnt[base + j];
    }
}

__global__ void k_scatter(const int* __restrict__ edge_index,
                          int* __restrict__ cursor, int* __restrict__ perm) {
    int e = blockIdx.x * blockDim.x + threadIdx.x;
    if (e < N_EDGES) {
        int pos = atomicAdd(&cursor[edge_index[N_EDGES + e]], 1);
        perm[pos] = e;
    }
}

// ---- lattice matrices ----
__global__ void k_latt(const float* __restrict__ lengths,
                       const float* __restrict__ angles,
                       float* __restrict__ latt) {
    int c = blockIdx.x * blockDim.x + threadIdx.x;
    if (c >= N_CRYST) return;
    float a  = lengths[c * 3 + 0];
    float b  = lengths[c * 3 + 1];
    float cc = lengths[c * 3 + 2];
    float al = angles[c * 3 + 0] * (PI_F / 180.0f);
    float be = angles[c * 3 + 1] * (PI_F / 180.0f);
    float ga = angles[c * 3 + 2] * (PI_F / 180.0f);
    float cos_a = cosf(al), cos_b = cosf(be), cos_g = cosf(ga);
    float sin_a = sinf(al), sin_b = sinf(be);
    float val = (cos_a * cos_b - cos_g) / (sin_a * sin_b);
    val = fminf(1.0f, fmaxf(-1.0f, val));
    float gs = acosf(val);
    float* L = latt + c * 9;
    L[0] = a * sin_b;              L[1] = 0.0f;                  L[2] = a * cos_b;
    L[3] = -b * sin_a * cosf(gs);  L[4] = b * sin_a * sinf(gs);  L[5] = b * cos_a;
    L[6] = 0.0f;                   L[7] = 0.0f;                  L[8] = cc;
}

// ---- cartesian coords ----
__global__ void k_cart(const float* __restrict__ frac,
                       const float* __restrict__ latt,
                       float* __restrict__ cart) {
    int n = blockIdx.x * blockDim.x + threadIdx.x;
    if (n >= N_ATOMS) return;
    int b = n / ATOMS_PER;
    const float* L = latt + b * 9;
    float f0 = frac[n * 3 + 0], f1 = frac[n * 3 + 1], f2 = frac[n * 3 + 2];
    cart[n * 3 + 0] = f0 * L[0] + f1 * L[3] + f2 * L[6];
    cart[n * 3 + 1] = f0 * L[1] + f1 * L[4] + f2 * L[7];
    cart[n * 3 + 2] = f0 * L[2] + f1 * L[5] + f2 * L[8];
}

// ---- rbf_h lookup table: T[j][c] = sum_k rbf_k(d_j) * W_rbf[k][c] ----
__global__ void k_tab(const float* __restrict__ W_rbf, float* __restrict__ T) {
    int j = blockIdx.x;       // 0..TABN+1
    int c = threadIdx.x;      // 0..127
    __shared__ float rbf[NRAD];
    float d = (float)j * (CUTOFF / TABN);
    const float inv2w2 = 1.0f / (2.0f * (CUTOFF / NRAD) * (CUTOFF / NRAD));
    const float cstep = CUTOFF / (NRAD - 1);
    float x = fminf(1.0f, d * (1.0f / CUTOFF));
    float env = 0.5f * (cosf(PI_F * x) + 1.0f);
    float diff = d - (float)c * cstep;
    rbf[c] = expf(-diff * diff * inv2w2) * env;
    __syncthreads();
    float acc = 0.0f;
#pragma unroll 8
    for (int k = 0; k < NRAD; k++) acc += rbf[k] * W_rbf[k * HID + c];
    T[j * HID + c] = acc;
}

// ---- weight prep: transpose + bf16 (Wt[col][k], k contiguous = B-fragment layout) ----
__global__ void k_prep(const float* __restrict__ W_edge,
                       const float* __restrict__ W_msg,
                       const float* __restrict__ W_gate,
                       const float* __restrict__ W_upd,
                       const float* __restrict__ W_atom,
                       ushort_t* __restrict__ Wt_edge,
                       ushort_t* __restrict__ Wt_msg,
                       ushort_t* __restrict__ Wt_gate,
                       ushort_t* __restrict__ Wt_upd,
                       ushort_t* __restrict__ Wt_atom) {
    int i = blockIdx.x * blockDim.x + threadIdx.x;
    if (i < 128 * 384) {
        int c = i / 384, k = i % 384;
        Wt_edge[(size_t)c * 384 + k] = f2bf(W_edge[k * 128 + c]);
    }
    if (i < 3 * 128 * 128) {
        int blk = i >> 14, r = i & 16383;
        int c = r >> 7, k = r & 127;
        Wt_msg[blk * 16384 + c * 128 + k]  = f2bf(W_msg[blk * 16384 + k * 128 + c]);
        Wt_gate[blk * 16384 + c * 128 + k] = f2bf(W_gate[blk * 16384 + k * 128 + c]);
        Wt_upd[blk * 16384 + c * 128 + k]  = f2bf(W_upd[blk * 16384 + k * 128 + c]);
    }
    if (i < 128 * 128) {
        int c = i >> 7, k = i & 127;
        Wt_atom[c * 128 + k] = (c < MAXZ) ? f2bf(W_atom[k * MAXZ + c]) : (ushort_t)0;
    }
}

// ---- h0 path (split): h0[n] = silu(embW[type[n]] + zW[batch[n]]) ----
__global__ void k_embW(const float* __restrict__ atom_emb,
                       const float* __restrict__ W_in,
                       const float* __restrict__ b_in,
                       float* __restrict__ embW) {
    int zi = blockIdx.x;
    int c = threadIdx.x;
    __shared__ float row[HID];
    row[c] = atom_emb[zi * HID + c];
    __syncthreads();
    float acc = b_in[c];
#pragma unroll 8
    for (int k = 0; k < HID; k++) acc += row[k] * W_in[k * HID + c];
    embW[zi * HID + c] = acc;
}

__global__ void k_zW(const float* __restrict__ z,
                     const float* __restrict__ W_in,
                     float* __restrict__ zW) {
    int b = blockIdx.x;
    int c = threadIdx.x;
    __shared__ float row[LAT];
    row[c]       = z[b * LAT + c];
    row[128 + c] = z[b * LAT + 128 + c];
    __syncthreads();
    float acc = 0.f;
#pragma unroll 8
    for (int k = 0; k < LAT; k++) acc += row[k] * W_in[(HID + k) * HID + c];
    zW[b * HID + c] = acc;
}

__global__ void k_h2(const int* __restrict__ types,
                     const float* __restrict__ embW,
                     const float* __restrict__ zW,
                     ushort_t* __restrict__ h_bf) {
    int idx = blockIdx.x * 256 + threadIdx.x;
    int n = idx >> 7, c = idx & 127;
    float v = embW[types[n] * HID + c] + zW[(n >> 6) * HID + c];
    h_bf[idx] = f2bf(silu(v));
}

// ---- Fused edge kernel: staged-h all-LDS GEMMs, M2T-overlays-HD, MFMA segment-sum ----
__global__ __launch_bounds__(512, 4)
void k_edges(const int* __restrict__ perm,
             const int* __restrict__ edge_index,
             const float* __restrict__ cart,
             const float* __restrict__ T,      // [TABN+2][HID] rbf_h table
             const ushort_t* __restrict__ h_bf,
             const ushort_t* __restrict__ Wt_edge,
             const float* __restrict__ b_edge,
             const ushort_t* __restrict__ Wt_msg,
             const float* __restrict__ b_msg,
             const ushort_t* __restrict__ Wt_gate,
             const float* __restrict__ W_force,
             float* __restrict__ agg,    // [NBLOCK][N_ATOMS][HID]
             float* __restrict__ outF)   // [N_ATOMS][3]
{
    __shared__ ushort_t R2[ETILE * HID];    // rbf_h (persists)
    __shared__ ushort_t HSR3[ETILE * HID];  // staged h_src, then running m
    __shared__ ushort_t HD[ETILE * HID];    // staged h_dst, then M2T (m2 transposed)
    __shared__ int   sm_dst[ETILE];
    __shared__ float sm_unit[ETILE][3];
    __shared__ float sm_d[ETILE];
    __shared__ float sm_f[ETILE];
    __shared__ uchar_t sm_runid8[ETILE];
    __shared__ int   sm_slotdst[ETILE];
    __shared__ int   sm_nruns;
    ushort_t* M2T = HD;    // HD is dead after GEMM2 (barrier B3a/B3b)

    const int t    = threadIdx.x;
    const int lane = t & 63;
    const int wave = t >> 6;             // 0..7
    const int l15  = lane & 15;
    const int g4   = lane >> 4;          // 0..3
    const int lk8  = 8 * g4;
    const int colw = wave * 16;          // this wave's 16 output cols
    const int e0   = blockIdx.x * ETILE;

    // per-lane static LDS addressing bases
    const int laneA = l15 * 256 + ((lk8 * 2) ^ ((l15 & 7) << 4));   // A-frag read base
    const int colM  = colw + l15;                                    // this lane's col
    int woff[4];                                                     // R3 C-write bases
#pragma unroll
    for (int r = 0; r < 4; r++) {
        int row = g4 * 4 + r;
        woff[r] = row * 256 + ((colM * 2) ^ ((row & 7) << 4));
    }

    // ---- Phase A: geometry ----
    if (t < ETILE) {
        int e = t;
        int eid = perm[e0 + e];
        int s = edge_index[eid];
        int d = edge_index[N_EDGES + eid];
        sm_dst[e] = d;
        float vx = cart[d * 3 + 0] - cart[s * 3 + 0];
        float vy = cart[d * 3 + 1] - cart[s * 3 + 1];
        float vz = cart[d * 3 + 2] - cart[s * 3 + 2];
        float dist = sqrtf(vx * vx + vy * vy + vz * vz) + 1e-8f;
        sm_d[e] = dist;
        float di = 1.0f / dist;
        sm_unit[e][0] = vx * di; sm_unit[e][1] = vy * di; sm_unit[e][2] = vz * di;
        sm_f[e] = 0.0f;
    }
    __syncthreads();   // B1

    // ---- issue h_src/h_dst tile loads (latency hidden under lerp phase) ----
    short8 hs[2], hd[2];
    int stoff[2];
#pragma unroll
    for (int p = 0; p < 2; p++) {
        int u   = p * 512 + t;       // 0..1023 = 64 rows x 16 chunks
        int row = u >> 4;
        int seg = u & 15;
        int eid = perm[e0 + row];
        int s = edge_index[eid];
        int d = edge_index[N_EDGES + eid];
        hs[p] = *reinterpret_cast<const short8*>(h_bf + (size_t)s * HID + seg * 8);
        hd[p] = *reinterpret_cast<const short8*>(h_bf + (size_t)d * HID + seg * 8);
        stoff[p] = swz(row, seg * 8);
    }

    // ---- run ids over sorted dst (wave 0, ballot) ----
    if (wave == 0) {
        int e = lane;
        int d = sm_dst[e];
        int prev = (e == 0) ? -1 : sm_dst[e - 1];
        ull_t mask = __ballot(d != prev);
        int rid = __popcll(mask & ((2ull << e) - 1)) - 1;
        sm_runid8[e] = (uchar_t)rid;
        if (d != prev) sm_slotdst[rid] = d;
        if (e == 0) sm_nruns = __popcll(mask);
    }

    // ---- Phase B: rbf_h via table lerp -> R2 ; write staged h tiles ----
    {
#pragma unroll
        for (int it = 0; it < 4; it++) {
            int u = it * 512 + t;          // 2048 units = 64 edges x 32 col-quads
            int e = u >> 5;
            int p = u & 31;                // cols 4p..4p+3
            float idxf = sm_d[e] * (TABN / CUTOFF);
            idxf = fminf(idxf, (float)TABN);
            int j = (int)idxf;
            float fr = idxf - (float)j;
            f32x4 lo = *reinterpret_cast<const f32x4*>(T + (size_t)j * HID + 4 * p);
            f32x4 hi = *reinterpret_cast<const f32x4*>(T + (size_t)(j + 1) * HID + 4 * p);
            float v0 = lo[0] + fr * (hi[0] - lo[0]);
            float v1 = lo[1] + fr * (hi[1] - lo[1]);
            float v2 = lo[2] + fr * (hi[2] - lo[2]);
            float v3 = lo[3] + fr * (hi[3] - lo[3]);
            unsigned int pk0 = pkbf(v0, v1);
            unsigned int pk1 = pkbf(v2, v3);
            int off = (e * 256 + 8 * p) ^ ((e & 7) << 4);
            *reinterpret_cast<unsigned int*>(reinterpret_cast<char*>(R2) + off)     = pk0;
            *reinterpret_cast<unsigned int*>(reinterpret_cast<char*>(R2) + off + 4) = pk1;
        }
        // staged h -> LDS (vmcnt waits inserted by compiler)
#pragma unroll
        for (int p = 0; p < 2; p++) {
            *reinterpret_cast<short8*>(reinterpret_cast<char*>(HSR3) + stoff[p]) = hs[p];
            *reinterpret_cast<short8*>(reinterpret_cast<char*>(HD)   + stoff[p]) = hd[p];
        }
    }
    __syncthreads();   // B2

    // ---- GEMM2 (all-LDS A): m0 = silu([h_src|h_dst|rbf_h] @ W_edge + b_edge) ----
    float m_acc[4][4];     // [at][r]
    {
        f32x4 am[4];
#pragma unroll
        for (int at = 0; at < 4; at++) am[at] = (f32x4){0.f, 0.f, 0.f, 0.f};
        const ushort_t* segp[3] = {HSR3, HD, R2};
#pragma unroll
        for (int seg = 0; seg < 3; seg++) {
#pragma unroll
            for (int ks = 0; ks < 4; ks++) {
                int kg = seg * 128 + ks * 32 + lk8;
                short8 B0 = ldB(Wt_edge, colM, 384, kg);
                int lA = laneA ^ (ks * 64);
#pragma unroll
                for (int at = 0; at < 4; at++) {
                    short8 A = *reinterpret_cast<const short8*>(
                        reinterpret_cast<const char*>(segp[seg]) + (lA + at * 4096));
                    am[at] = MFMA(A, B0, am[at]);
                }
            }
        }
        float be0 = b_edge[colM];
#pragma unroll
        for (int at = 0; at < 4; at++)
#pragma unroll
            for (int r = 0; r < 4; r++)
                m_acc[at][r] = silu(am[at][r] + be0);
    }
    __syncthreads();   // B3a: all HSR3/HD reads complete

    // publish m -> HSR3 (now R3)
#pragma unroll
    for (int at = 0; at < 4; at++)
#pragma unroll
        for (int r = 0; r < 4; r++)
            *reinterpret_cast<ushort_t*>(reinterpret_cast<char*>(HSR3) +
                (woff[r] + at * 4096)) = f2bf(m_acc[at][r]);
    __syncthreads();   // B3b

    // ---- message blocks ----
    for (int i = 0; i < NBLOCK; i++) {
        const ushort_t* Wm = Wt_msg  + i * 16384;
        const ushort_t* Wg = Wt_gate + i * 16384;
        float* aggp = agg + (size_t)i * N_ATOMS * HID;
        // P1: msg + gate GEMMs; epilogue -> M2T (transposed, b64-packed)
        {
            float bm = b_msg[i * HID + colM];
            f32x4 am_[4], ag_[4];
#pragma unroll
            for (int at = 0; at < 4; at++) {
                am_[at] = (f32x4){0.f, 0.f, 0.f, 0.f};
                ag_[at] = (f32x4){0.f, 0.f, 0.f, 0.f};
            }
#pragma unroll
            for (int ks = 0; ks < 4; ks++) {
                short8 Bm = ldB(Wm, colM, 128, ks * 32 + lk8);
                short8 Bg = ldB(Wg, colM, 128, ks * 32 + lk8);
                int lA = laneA ^ (ks * 64);
#pragma unroll
                for (int at = 0; at < 4; at++) {
                    short8 Am = *reinterpret_cast<const short8*>(
                        reinterpret_cast<const char*>(HSR3) + (lA + at * 4096));
                    short8 Ag = *reinterpret_cast<const short8*>(
                        reinterpret_cast<const char*>(R2) + (lA + at * 4096));
                    am_[at] = MFMA(Am, Bm, am_[at]);
                    ag_[at] = MFMA(Ag, Bg, ag_[at]);
                }
            }
#pragma unroll
            for (int at = 0; at < 4; at++) {
                float m2v[4];
#pragma unroll
                for (int r = 0; r < 4; r++) {
                    float m2 = silu(am_[at][r] + bm) * ag_[at][r];
                    m2v[r] = m2;
                    m_acc[at][r] += m2;
                }
                unsigned int plo = pkbf(m2v[0], m2v[1]);
                unsigned int phi = pkbf(m2v[2], m2v[3]);
                ull_t pk = ((ull_t)phi << 32) | plo;
                int addr = (colM * 128 + (at * 16 + g4 * 4) * 2) ^ ((colM & 7) << 4);
                *reinterpret_cast<ull_t*>(reinterpret_cast<char*>(M2T) + addr) = pk;
            }
        }
        __syncthreads();   // Ba: M2T complete; all R3/R2 reads done

        // P2: segment sum via MFMA: agg[run][c] = sum_e S[run][e] * m2[e][c]
        {
            int nruns = sm_nruns;
            short8 Bm2[2];
#pragma unroll
            for (int ks = 0; ks < 2; ks++) {
                int addr = (colM * 128 + (ks * 32 + lk8) * 2) ^ ((colM & 7) << 4);
                Bm2[ks] = *reinterpret_cast<const short8*>(
                    reinterpret_cast<const char*>(M2T) + addr);
            }
            for (int rt = 0; rt * 16 < nruns; rt++) {
                int tv = l15 + rt * 16;       // run this lane's A-row represents
                short8 SA[2];
#pragma unroll
                for (int ks = 0; ks < 2; ks++) {
                    ull_t rid8 = *reinterpret_cast<const ull_t*>(sm_runid8 + ks * 32 + lk8);
                    unsigned int rlo = (unsigned int)rid8;
                    unsigned int rhi = (unsigned int)(rid8 >> 32);
                    union { unsigned int u[4]; short8 s8; } sb;
#pragma unroll
                    for (int q = 0; q < 2; q++) {
                        unsigned int rr = q ? rhi : rlo;
                        unsigned int w0 = 0, w1 = 0;
                        if ((int)((rr >>  0) & 255) == tv) w0 |= 0x3F80u;
                        if ((int)((rr >>  8) & 255) == tv) w0 |= 0x3F800000u;
                        if ((int)((rr >> 16) & 255) == tv) w1 |= 0x3F80u;
                        if ((int)((rr >> 24) & 255) == tv) w1 |= 0x3F800000u;
                        sb.u[q * 2]     = w0;
                        sb.u[q * 2 + 1] = w1;
                    }
                    SA[ks] = sb.s8;
                }
                f32x4 acc0 = {0.f, 0.f, 0.f, 0.f};
                acc0 = MFMA(SA[0], Bm2[0], acc0);
                acc0 = MFMA(SA[1], Bm2[1], acc0);
#pragma unroll
                for (int r = 0; r < 4; r++) {
                    int run = rt * 16 + g4 * 4 + r;
                    if (run < nruns) {
                        int d = sm_slotdst[run];
                        atomicAdd(&aggp[(size_t)d * HID + colM], acc0[r]);
                    }
                }
            }
        }

        // publish updated m (R3; reads of old R3 finished at Ba)
        if (i < NBLOCK - 1) {
#pragma unroll
            for (int at = 0; at < 4; at++)
#pragma unroll
                for (int r = 0; r < 4; r++)
                    *reinterpret_cast<ushort_t*>(reinterpret_cast<char*>(HSR3) +
                        (woff[r] + at * 4096)) = f2bf(m_acc[at][r]);
        }
        __syncthreads();   // Bb: R3 ready, M2T free
    }

    // ---- force: f_e = m . W_force ; run-aggregated outF[dst] += f_e * unit ----
    {
        float wf0 = W_force[colM];
#pragma unroll
        for (int at = 0; at < 4; at++)
#pragma unroll
            for (int r = 0; r < 4; r++) {
                float part = m_acc[at][r] * wf0;
                part += __shfl_xor(part, 1, 64);
                part += __shfl_xor(part, 2, 64);
                part += __shfl_xor(part, 4, 64);
                part += __shfl_xor(part, 8, 64);
                if (l15 == 0)
                    atomicAdd(&sm_f[at * 16 + g4 * 4 + r], part);
            }
        __syncthreads();
        if (t < ETILE) {
            int e = t;
            int d = sm_dst[e];
            if (e == 0 || sm_dst[e - 1] != d) {
                float fx = 0.f, fy = 0.f, fz = 0.f;
                int j = e;
                do {
                    float f = sm_f[j];
                    fx += f * sm_unit[j][0];
                    fy += f * sm_unit[j][1];
                    fz += f * sm_unit[j][2];
                    j++;
                } while (j < ETILE && sm_dst[j] == d);
                atomicAdd(&outF[d * 3 + 0], fx);
                atomicAdd(&outF[d * 3 + 1], fy);
                atomicAdd(&outF[d * 3 + 2], fz);
            }
        }
    }
}

// ---- Atom-side (MFMA): h = h0 + sum_i silu(agg_i @ W_upd_i + b); out = h @ W_atom + b ----
__global__ __launch_bounds__(256)
void k_atom2(const float* __restrict__ agg,
             const ushort_t* __restrict__ Wt_upd,    // [3][128 col][128 k]
             const float* __restrict__ b_upd,
             const ushort_t* __restrict__ Wt_atom,   // [128 col(pad)][128 k]
             const float* __restrict__ b_atom,
             const ushort_t* __restrict__ h_bf,
             float* __restrict__ out) {
    __shared__ ushort_t RA[64 * HID];   // 16 KB staged A tile

    const int t    = threadIdx.x;
    const int lane = t & 63;
    const int wave = t >> 6;
    const int l15  = lane & 15;
    const int lk8  = 8 * (lane >> 4);
    const int colw = wave * 32;
    const int n0   = blockIdx.x * 64;

    const int laneA = l15 * 256 + ((lk8 * 2) ^ ((l15 & 7) << 4));
    int woff[2][4];
#pragma unroll
    for (int nt = 0; nt < 2; nt++)
#pragma unroll
        for (int r = 0; r < 4; r++) {
            int row = (lane >> 4) * 4 + r;
            woff[nt][r] = row * 256 + (((colw + nt * 16 + l15) * 2) ^ ((row & 7) << 4));
        }

    // h0 in C-layout f32 regs
    float h_acc[4][2][4];
#pragma unroll
    for (int at = 0; at < 4; at++)
#pragma unroll
        for (int nt = 0; nt < 2; nt++)
#pragma unroll
            for (int r = 0; r < 4; r++) {
                int row = at * 16 + (lane >> 4) * 4 + r;
                h_acc[at][nt][r] = bf2f(h_bf[(size_t)(n0 + row) * HID + colw + nt * 16 + l15]);
            }

    for (int i = 0; i < NBLOCK; i++) {
        // stage agg_i tile -> RA (f32 -> bf16, swizzled); coalesced f32x4 loads
        const float* ap = agg + (size_t)i * N_ATOMS * HID + (size_t)n0 * HID;
#pragma unroll
        for (int it = 0; it < 8; it++) {
            int u = it * 256 + t;
            int row = u >> 5, p = u & 31;
            f32x4 v = *reinterpret_cast<const f32x4*>(ap + (size_t)row * HID + 4 * p);
            unsigned int pk0 = pkbf(v[0], v[1]);
            unsigned int pk1 = pkbf(v[2], v[3]);
            int off = (row * 256 + 8 * p) ^ ((row & 7) << 4);
            *reinterpret_cast<unsigned int*>(reinterpret_cast<char*>(RA) + off)     = pk0;
            *reinterpret_cast<unsigned int*>(reinterpret_cast<char*>(RA) + off + 4) = pk1;
        }
        __syncthreads();

        const ushort_t* Wu = Wt_upd + i * 16384;
        float bu0 = b_upd[i * HID + colw + l15];
        float bu1 = b_upd[i * HID + colw + 16 + l15];
        f32x4 am[4][2];
#pragma unroll
        for (int at = 0; at < 4; at++)
#pragma unroll
            for (int nt = 0; nt < 2; nt++)
                am[at][nt] = (f32x4){0.f, 0.f, 0.f, 0.f};
#pragma unroll
        for (int ks = 0; ks < 4; ks++) {
            short8 B0 = ldB(Wu, colw + l15,      128, ks * 32 + lk8);
            short8 B1 = ldB(Wu, colw + 16 + l15, 128, ks * 32 + lk8);
            int lA = laneA ^ (ks * 64);
#pragma unroll
            for (int at = 0; at < 4; at++) {
                short8 A = *reinterpret_cast<const short8*>(
                    reinterpret_cast<const char*>(RA) + (lA + at * 4096));
                am[at][0] = MFMA(A, B0, am[at][0]);
                am[at][1] = MFMA(A, B1, am[at][1]);
            }
        }
#pragma unroll
        for (int at = 0; at < 4; at++)
#pragma unroll
            for (int r = 0; r < 4; r++) {
                h_acc[at][0][r] += silu(am[at][0][r] + bu0);
                h_acc[at][1][r] += silu(am[at][1][r] + bu1);
            }
        __syncthreads();
    }

    // publish h -> RA (bf16), head GEMM
#pragma unroll
    for (int at = 0; at < 4; at++)
#pragma unroll
        for (int nt = 0; nt < 2; nt++)
#pragma unroll
            for (int r = 0; r < 4; r++)
                *reinterpret_cast<ushort_t*>(reinterpret_cast<char*>(RA) +
                    (woff[nt][r] + at * 4096)) = f2bf(h_acc[at][nt][r]);
    __syncthreads();

    {
        f32x4 am[4][2];
#pragma unroll
        for (int at = 0; at < 4; at++)
#pragma unroll
            for (int nt = 0; nt < 2; nt++)
                am[at][nt] = (f32x4){0.f, 0.f, 0.f, 0.f};
#pragma unroll
        for (int ks = 0; ks < 4; ks++) {
            short8 B0 = ldB(Wt_atom, colw + l15,      128, ks * 32 + lk8);
            short8 B1 = ldB(Wt_atom, colw + 16 + l15, 128, ks * 32 + lk8);
            int lA = laneA ^ (ks * 64);
#pragma unroll
            for (int at = 0; at < 4; at++) {
                short8 A = *reinterpret_cast<const short8*>(
                    reinterpret_cast<const char*>(RA) + (lA + at * 4096));
                am[at][0] = MFMA(A, B0, am[at][0]);
                am[at][1] = MFMA(A, B1, am[at][1]);
            }
        }
        int col0 = colw + l15;
        int col1 = colw + 16 + l15;
        float ba0 = (col0 < MAXZ) ? b_atom[col0] : 0.f;
        float ba1 = (col1 < MAXZ) ? b_atom[col1] : 0.f;
#pragma unroll
        for (int at = 0; at < 4; at++)
#pragma unroll
            for (int r = 0; r < 4; r++) {
                int row = n0 + at * 16 + (lane >> 4) * 4 + r;
                if (col0 < MAXZ)
                    out[(size_t)N_ATOMS * 3 + (size_t)row * MAXZ + col0] = am[at][0][r] + ba0;
                if (col1 < MAXZ)
                    out[(size_t)N_ATOMS * 3 + (size_t)row * MAXZ + col1] = am[at][1][r] + ba1;
            }
    }
}

extern "C" void kernel_launch(void* const* d_in, const int* in_sizes, int n_in,
                              void* d_out, int out_size, void* d_ws, size_t ws_size,
                              hipStream_t stream) {
    const float* z         = (const float*)d_in[0];
    const float* frac      = (const float*)d_in[1];
    const int*   types     = (const int*)d_in[2];
    const float* lengths   = (const float*)d_in[4];
    const float* angles    = (const float*)d_in[5];
    const int*   edge_idx  = (const int*)d_in[6];
    const float* atom_emb  = (const float*)d_in[7];
    const float* W_in      = (const float*)d_in[8];
    const float* b_in      = (const float*)d_in[9];
    const float* W_rbf     = (const float*)d_in[10];
    const float* W_edge    = (const float*)d_in[11];
    const float* b_edge    = (const float*)d_in[12];
    const float* W_msg     = (const float*)d_in[13];
    const float* b_msg     = (const float*)d_in[14];
    const float* W_gate    = (const float*)d_in[15];
    const float* W_upd     = (const float*)d_in[16];
    const float* b_upd     = (const float*)d_in[17];
    const float* W_force   = (const float*)d_in[18];
    const float* W_atom    = (const float*)d_in[19];
    const float* b_atom    = (const float*)d_in[20];

    float* out = (float*)d_out;

    // workspace layout
    float* ws = (float*)d_ws;
    size_t off = 0;
    float* latt = ws + off; off += N_CRYST * 9;
    float* cart = ws + off; off += (size_t)N_ATOMS * 3;
    float* agg  = ws + off; off += (size_t)NBLOCK * N_ATOMS * HID;
    float* embW = ws + off; off += MAXZ * HID;
    float* zW   = ws + off; off += N_CRYST * HID;
    float* T    = ws + off; off += (size_t)(TABN + 2) * HID;
    int* cnt    = (int*)(ws + off); off += N_ATOMS;
    int* cursor = (int*)(ws + off); off += N_ATOMS;
    int* perm   = (int*)(ws + off); off += N_EDGES;
    off = (off + 7) & ~(size_t)7;
    ushort_t* ub = (ushort_t*)(ws + off);
    size_t uoff = 0;
    ushort_t* h_bf    = ub + uoff; uoff += (size_t)N_ATOMS * HID;
    ushort_t* Wt_edge = ub + uoff; uoff += 128 * 384;
    ushort_t* Wt_msg  = ub + uoff; uoff += 3 * 128 * 128;
    ushort_t* Wt_gate = ub + uoff; uoff += 3 * 128 * 128;
    ushort_t* Wt_upd  = ub + uoff; uoff += 3 * 128 * 128;
    ushort_t* Wt_atom = ub + uoff; uoff += 128 * 128;

    // fused zero-init (out force region, agg, cnt)
    k_init<<<(NBLOCK * N_ATOMS * HID + 255) / 256, 256, 0, stream>>>(out, agg, cnt);

    // counting sort by dst
    k_hist<<<(N_EDGES + 255) / 256, 256, 0, stream>>>(edge_idx, cnt);
    k_scan<<<1, 256, 0, stream>>>(cnt, cursor);
    k_scatter<<<(N_EDGES + 255) / 256, 256, 0, stream>>>(edge_idx, cursor, perm);

    k_latt<<<1, 256, 0, stream>>>(lengths, angles, latt);
    k_cart<<<(N_ATOMS + 255) / 256, 256, 0, stream>>>(frac, latt, cart);
    k_tab<<<TABN + 2, HID, 0, stream>>>(W_rbf, T);
    k_prep<<<192, 256, 0, stream>>>(W_edge, W_msg, W_gate, W_upd, W_atom,
                                    Wt_edge, Wt_msg, Wt_gate, Wt_upd, Wt_atom);

    // h0 path
    k_embW<<<MAXZ, HID, 0, stream>>>(atom_emb, W_in, b_in, embW);
    k_zW<<<N_CRYST, HID, 0, stream>>>(z, W_in, zW);
    k_h2<<<(N_ATOMS * HID) / 256, 256, 0, stream>>>(types, embW, zW, h_bf);

    k_edges<<<N_EDGES / ETILE, 512, 0, stream>>>(perm, edge_idx, cart, T, h_bf,
                                                 Wt_edge, b_edge,
                                                 Wt_msg, b_msg, Wt_gate, W_force,
                                                 agg, out);

    k_atom2<<<N_ATOMS / 64, 256, 0, stream>>>(agg, Wt_upd, b_upd, Wt_atom, b_atom,
                                              h_bf, out);
}

// Round 13
// 366.946 us; speedup vs baseline: 1.2270x; 1.0723x over previous
//
#include <hip/hip_runtime.h>
#include <hip/hip_bf16.h>

#define N_CRYST 256
#define ATOMS_PER 64
#define N_ATOMS (N_CRYST * ATOMS_PER)   // 16384
#define N_EDGES (N_ATOMS * 20)          // 327680
#define HID 128
#define LAT 256
#define NRAD 128
#define NBLOCK 3
#define MAXZ 100
#define CUTOFF 6.0f
#define PI_F 3.14159265358979323846f
#define ETILE 64
#define TABN 2048                        // table intervals over [0, CUTOFF]

typedef unsigned short ushort_t;
typedef unsigned char uchar_t;
typedef unsigned long long ull_t;
typedef __attribute__((ext_vector_type(8))) short short8;
typedef __attribute__((ext_vector_type(4))) float f32x4;

__device__ __forceinline__ float fexp2(float x) {
    float r; asm("v_exp_f32 %0, %1" : "=v"(r) : "v"(x)); return r;
}
__device__ __forceinline__ float frcp(float x) {
    float r; asm("v_rcp_f32 %0, %1" : "=v"(r) : "v"(x)); return r;
}
// silu(x) = x / (1 + exp(-x)) = x * rcp(1 + 2^(-x*log2e))
__device__ __forceinline__ float silu(float x) {
    return x * frcp(1.0f + fexp2(x * -1.44269504f));
}

__device__ __forceinline__ ushort_t f2bf(float v) {          // fast RNE (finite inputs)
    unsigned int u = __float_as_uint(v);
    return (ushort_t)((u + 0x7FFF + ((u >> 16) & 1)) >> 16);
}
__device__ __forceinline__ float bf2f(ushort_t u) {
    return __uint_as_float((unsigned int)u << 16);
}
// packed bf16 convert: dst.lo = bf16(lo), dst.hi = bf16(hi) — 1 VALU instr
__device__ __forceinline__ unsigned int pkbf(float lo, float hi) {
    unsigned int r;
    asm("v_cvt_pk_bf16_f32 %0, %1, %2" : "=v"(r) : "v"(lo), "v"(hi));
    return r;
}

__device__ __forceinline__ f32x4 MFMA(short8 a, short8 b, f32x4 c) {
    return __builtin_amdgcn_mfma_f32_16x16x32_bf16(a, b, c, 0, 0, 0);
}

// swizzled byte offset for [64][128] bf16 LDS tiles: (row*256 + col*2) ^ ((row&7)<<4)
__device__ __forceinline__ int swz(int row, int k) {
    return (row * 256 + k * 2) ^ ((row & 7) << 4);
}

__device__ __forceinline__ short8 ldB(const ushort_t* W, int col, int K, int k) {
    return *reinterpret_cast<const short8*>(W + (size_t)col * K + k);
}

// ---- fused zero-init: out force region, agg, cnt ----
__global__ void k_init(float* __restrict__ out, float* __restrict__ agg,
                       int* __restrict__ cnt) {
    int i = blockIdx.x * blockDim.x + threadIdx.x;
    if (i < N_ATOMS * 3) out[i] = 0.0f;
    if (i < N_ATOMS) cnt[i] = 0;
    if (i < NBLOCK * N_ATOMS * HID) agg[i] = 0.0f;
}

// ---- exclusive scan of 16384 counts (single block, 256 threads) ----
__global__ void k_scan(const int* __restrict__ cnt, int* __restrict__ cursor) {
    __shared__ int partial[256];
    int t = threadIdx.x;
    int base = t * (N_ATOMS / 256);
    int s = 0;
    for (int j = 0; j < N_ATOMS / 256; j++) s += cnt[base + j];
    partial[t] = s;
    __syncthreads();
    if (t == 0) {
        int run = 0;
        for (int i = 0; i < 256; i++) { int v = partial[i]; partial[i] = run; run += v; }
    }
    __syncthreads();
    int run = partial[t];
    for (int j = 0; j < N_ATOMS / 256; j++) {
        cursor[base + j] = run;
        run += cnt[base + j];
    }
}

// ---- fused preprocessing: hist | cart(+inline latt) | rbf_h table | weight prep | embW | zW ----
// role ranges (256-thread blocks):
//   [0,1280)      hist
//   [1280,1344)   cart (lattice computed inline per thread)
//   [1344,2369)   T table, 2 rows per block
//   [2369,2561)   weight transpose/bf16
//   [2561,2611)   embW, 2 rows per block
//   [2611,2739)   zW, 2 rows per block
#define F0_HIST 1280
#define F0_CART (F0_HIST + 64)
#define F0_TAB  (F0_CART + 1025)
#define F0_PREP (F0_TAB + 192)
#define F0_EMBW (F0_PREP + 50)
#define F0_ZW   (F0_EMBW + 128)
__global__ void k_fuse0(const int* __restrict__ edge_index, int* __restrict__ cnt,
                        const float* __restrict__ lengths, const float* __restrict__ angles,
                        const float* __restrict__ frac, float* __restrict__ cart,
                        const float* __restrict__ W_rbf, float* __restrict__ T,
                        const float* __restrict__ W_edge, const float* __restrict__ W_msg,
                        const float* __restrict__ W_gate, const float* __restrict__ W_upd,
                        const float* __restrict__ W_atom,
                        ushort_t* __restrict__ Wt_edge, ushort_t* __restrict__ Wt_msg,
                        ushort_t* __restrict__ Wt_gate, ushort_t* __restrict__ Wt_upd,
                        ushort_t* __restrict__ Wt_atom,
                        const float* __restrict__ atom_emb, const float* __restrict__ W_in,
                        const float* __restrict__ b_in, float* __restrict__ embW,
                        const float* __restrict__ z, float* __restrict__ zW) {
    __shared__ float sh[512];
    int b = blockIdx.x, t = threadIdx.x;
    if (b < F0_HIST) {
        int e = b * 256 + t;
        atomicAdd(&cnt[edge_index[N_EDGES + e]], 1);
    } else if (b < F0_CART) {
        int n = (b - F0_HIST) * 256 + t;
        int c = n >> 6;   // crystal
        float a  = lengths[c * 3 + 0];
        float bb = lengths[c * 3 + 1];
        float cc = lengths[c * 3 + 2];
        float al = angles[c * 3 + 0] * (PI_F / 180.0f);
        float be = angles[c * 3 + 1] * (PI_F / 180.0f);
        float ga = angles[c * 3 + 2] * (PI_F / 180.0f);
        float cos_a = cosf(al), cos_b = cosf(be), cos_g = cosf(ga);
        float sin_a = sinf(al), sin_b = sinf(be);
        float val = (cos_a * cos_b - cos_g) / (sin_a * sin_b);
        val = fminf(1.0f, fmaxf(-1.0f, val));
        float gs = acosf(val);
        float L0 = a * sin_b, L2 = a * cos_b;
        float L3 = -bb * sin_a * cosf(gs), L4 = bb * sin_a * sinf(gs), L5 = bb * cos_a;
        float f0 = frac[n * 3 + 0], f1 = frac[n * 3 + 1], f2 = frac[n * 3 + 2];
        cart[n * 3 + 0] = f0 * L0 + f1 * L3;
        cart[n * 3 + 1] = f1 * L4;
        cart[n * 3 + 2] = f0 * L2 + f1 * L5 + f2 * cc;
    } else if (b < F0_TAB) {
        int half = t >> 7, c = t & 127;
        int j = (b - F0_CART) * 2 + half;   // 0..2049
        float d = (float)j * (CUTOFF / TABN);
        const float inv2w2 = 1.0f / (2.0f * (CUTOFF / NRAD) * (CUTOFF / NRAD));
        const float cstep = CUTOFF / (NRAD - 1);
        float x = fminf(1.0f, d * (1.0f / CUTOFF));
        float env = 0.5f * (cosf(PI_F * x) + 1.0f);
        float diff = d - (float)c * cstep;
        sh[half * 128 + c] = expf(-diff * diff * inv2w2) * env;
        __syncthreads();
        float acc = 0.0f;
#pragma unroll 8
        for (int k = 0; k < NRAD; k++) acc += sh[half * 128 + k] * W_rbf[k * HID + c];
        T[(size_t)j * HID + c] = acc;
    } else if (b < F0_PREP) {
        int i = (b - F0_TAB) * 256 + t;     // < 49152
        {
            int c = i / 384, k = i % 384;
            Wt_edge[(size_t)c * 384 + k] = f2bf(W_edge[k * 128 + c]);
        }
        {
            int blk = i >> 14, r = i & 16383;
            int c = r >> 7, k = r & 127;
            Wt_msg[blk * 16384 + c * 128 + k]  = f2bf(W_msg[blk * 16384 + k * 128 + c]);
            Wt_gate[blk * 16384 + c * 128 + k] = f2bf(W_gate[blk * 16384 + k * 128 + c]);
            Wt_upd[blk * 16384 + c * 128 + k]  = f2bf(W_upd[blk * 16384 + k * 128 + c]);
        }
        if (i < 128 * 128) {
            int c = i >> 7, k = i & 127;
            Wt_atom[c * 128 + k] = (c < MAXZ) ? f2bf(W_atom[k * MAXZ + c]) : (ushort_t)0;
        }
    } else if (b < F0_EMBW) {
        int half = t >> 7, c = t & 127;
        int zi = (b - F0_PREP) * 2 + half;  // 0..99
        sh[half * 128 + c] = atom_emb[zi * HID + c];
        __syncthreads();
        float acc = b_in[c];
#pragma unroll 8
        for (int k = 0; k < HID; k++) acc += sh[half * 128 + k] * W_in[k * HID + c];
        embW[zi * HID + c] = acc;
    } else {
        int half = t >> 7, c = t & 127;
        int bc = (b - F0_EMBW) * 2 + half;  // 0..255
        sh[half * 256 + c]       = z[bc * LAT + c];
        sh[half * 256 + 128 + c] = z[bc * LAT + 128 + c];
        __syncthreads();
        float acc = 0.f;
#pragma unroll 8
        for (int k = 0; k < LAT; k++) acc += sh[half * 256 + k] * W_in[(HID + k) * HID + c];
        zW[bc * HID + c] = acc;
    }
}

// ---- fused: scatter (needs scan) + h0 gather/silu ----
__global__ void k_fuse1(const int* __restrict__ edge_index,
                        int* __restrict__ cursor, int* __restrict__ perm,
                        const int* __restrict__ types,
                        const float* __restrict__ embW, const float* __restrict__ zW,
                        ushort_t* __restrict__ h_bf) {
    int b = blockIdx.x, t = threadIdx.x;
    if (b < 1280) {
        int e = b * 256 + t;
        int pos = atomicAdd(&cursor[edge_index[N_EDGES + e]], 1);
        perm[pos] = e;
    } else {
        int idx = (b - 1280) * 256 + t;
        int n = idx >> 7, c = idx & 127;
        float v = embW[types[n] * HID + c] + zW[(n >> 6) * HID + c];
        h_bf[idx] = f2bf(silu(v));
    }
}

// ---- Fused edge kernel: staged-h all-LDS GEMMs, M2T-overlays-HD, MFMA segment-sum ----
__global__ __launch_bounds__(512, 4)
void k_edges(const int* __restrict__ perm,
             const int* __restrict__ edge_index,
             const float* __restrict__ cart,
             const float* __restrict__ T,      // [TABN+2][HID] rbf_h table
             const ushort_t* __restrict__ h_bf,
             const ushort_t* __restrict__ Wt_edge,
             const float* __restrict__ b_edge,
             const ushort_t* __restrict__ Wt_msg,
             const float* __restrict__ b_msg,
             const ushort_t* __restrict__ Wt_gate,
             const float* __restrict__ W_force,
             float* __restrict__ agg,    // [NBLOCK][N_ATOMS][HID]
             float* __restrict__ outF)   // [N_ATOMS][3]
{
    __shared__ ushort_t R2[ETILE * HID];    // rbf_h (persists)
    __shared__ ushort_t HSR3[ETILE * HID];  // staged h_src, then running m
    __shared__ ushort_t HD[ETILE * HID];    // staged h_dst, then M2T (m2 transposed)
    __shared__ int   sm_dst[ETILE];
    __shared__ float sm_unit[ETILE][3];
    __shared__ float sm_d[ETILE];
    __shared__ float sm_f[ETILE];
    __shared__ uchar_t sm_runid8[ETILE];
    __shared__ int   sm_slotdst[ETILE];
    __shared__ int   sm_nruns;
    ushort_t* M2T = HD;    // HD is dead after GEMM2 (barrier B3a/B3b)

    const int t    = threadIdx.x;
    const int lane = t & 63;
    const int wave = t >> 6;             // 0..7
    const int l15  = lane & 15;
    const int g4   = lane >> 4;          // 0..3
    const int lk8  = 8 * g4;
    const int colw = wave * 16;          // this wave's 16 output cols
    const int e0   = blockIdx.x * ETILE;

    // per-lane static LDS addressing bases
    const int laneA = l15 * 256 + ((lk8 * 2) ^ ((l15 & 7) << 4));   // A-frag read base
    const int colM  = colw + l15;                                    // this lane's col
    int woff[4];                                                     // R3 C-write bases
#pragma unroll
    for (int r = 0; r < 4; r++) {
        int row = g4 * 4 + r;
        woff[r] = row * 256 + ((colM * 2) ^ ((row & 7) << 4));
    }

    // ---- Phase A: geometry ----
    if (t < ETILE) {
        int e = t;
        int eid = perm[e0 + e];
        int s = edge_index[eid];
        int d = edge_index[N_EDGES + eid];
        sm_dst[e] = d;
        float vx = cart[d * 3 + 0] - cart[s * 3 + 0];
        float vy = cart[d * 3 + 1] - cart[s * 3 + 1];
        float vz = cart[d * 3 + 2] - cart[s * 3 + 2];
        float dist = sqrtf(vx * vx + vy * vy + vz * vz) + 1e-8f;
        sm_d[e] = dist;
        float di = 1.0f / dist;
        sm_unit[e][0] = vx * di; sm_unit[e][1] = vy * di; sm_unit[e][2] = vz * di;
        sm_f[e] = 0.0f;
    }
    __syncthreads();   // B1

    // ---- issue h_src/h_dst tile loads (latency hidden under lerp phase) ----
    short8 hs[2], hd[2];
    int stoff[2];
#pragma unroll
    for (int p = 0; p < 2; p++) {
        int u   = p * 512 + t;       // 0..1023 = 64 rows x 16 chunks
        int row = u >> 4;
        int seg = u & 15;
        int eid = perm[e0 + row];
        int s = edge_index[eid];
        int d = edge_index[N_EDGES + eid];
        hs[p] = *reinterpret_cast<const short8*>(h_bf + (size_t)s * HID + seg * 8);
        hd[p] = *reinterpret_cast<const short8*>(h_bf + (size_t)d * HID + seg * 8);
        stoff[p] = swz(row, seg * 8);
    }

    // ---- run ids over sorted dst (wave 0, ballot) ----
    if (wave == 0) {
        int e = lane;
        int d = sm_dst[e];
        int prev = (e == 0) ? -1 : sm_dst[e - 1];
        ull_t mask = __ballot(d != prev);
        int rid = __popcll(mask & ((2ull << e) - 1)) - 1;
        sm_runid8[e] = (uchar_t)rid;
        if (d != prev) sm_slotdst[rid] = d;
        if (e == 0) sm_nruns = __popcll(mask);
    }

    // ---- Phase B: rbf_h via table lerp -> R2 ; write staged h tiles ----
    {
#pragma unroll
        for (int it = 0; it < 4; it++) {
            int u = it * 512 + t;          // 2048 units = 64 edges x 32 col-quads
            int e = u >> 5;
            int p = u & 31;                // cols 4p..4p+3
            float idxf = sm_d[e] * (TABN / CUTOFF);
            idxf = fminf(idxf, (float)TABN);
            int j = (int)idxf;
            float fr = idxf - (float)j;
            f32x4 lo = *reinterpret_cast<const f32x4*>(T + (size_t)j * HID + 4 * p);
            f32x4 hi = *reinterpret_cast<const f32x4*>(T + (size_t)(j + 1) * HID + 4 * p);
            float v0 = lo[0] + fr * (hi[0] - lo[0]);
            float v1 = lo[1] + fr * (hi[1] - lo[1]);
            float v2 = lo[2] + fr * (hi[2] - lo[2]);
            float v3 = lo[3] + fr * (hi[3] - lo[3]);
            unsigned int pk0 = pkbf(v0, v1);
            unsigned int pk1 = pkbf(v2, v3);
            int off = (e * 256 + 8 * p) ^ ((e & 7) << 4);
            *reinterpret_cast<unsigned int*>(reinterpret_cast<char*>(R2) + off)     = pk0;
            *reinterpret_cast<unsigned int*>(reinterpret_cast<char*>(R2) + off + 4) = pk1;
        }
        // staged h -> LDS (vmcnt waits inserted by compiler)
#pragma unroll
        for (int p = 0; p < 2; p++) {
            *reinterpret_cast<short8*>(reinterpret_cast<char*>(HSR3) + stoff[p]) = hs[p];
            *reinterpret_cast<short8*>(reinterpret_cast<char*>(HD)   + stoff[p]) = hd[p];
        }
    }
    __syncthreads();   // B2

    // ---- GEMM2 (all-LDS A): m0 = silu([h_src|h_dst|rbf_h] @ W_edge + b_edge) ----
    float m_acc[4][4];     // [at][r]
    {
        f32x4 am[4];
#pragma unroll
        for (int at = 0; at < 4; at++) am[at] = (f32x4){0.f, 0.f, 0.f, 0.f};
        const ushort_t* segp[3] = {HSR3, HD, R2};
#pragma unroll
        for (int seg = 0; seg < 3; seg++) {
#pragma unroll
            for (int ks = 0; ks < 4; ks++) {
                int kg = seg * 128 + ks * 32 + lk8;
                short8 B0 = ldB(Wt_edge, colM, 384, kg);
                int lA = laneA ^ (ks * 64);
#pragma unroll
                for (int at = 0; at < 4; at++) {
                    short8 A = *reinterpret_cast<const short8*>(
                        reinterpret_cast<const char*>(segp[seg]) + (lA + at * 4096));
                    am[at] = MFMA(A, B0, am[at]);
                }
            }
        }
        float be0 = b_edge[colM];
#pragma unroll
        for (int at = 0; at < 4; at++)
#pragma unroll
            for (int r = 0; r < 4; r++)
                m_acc[at][r] = silu(am[at][r] + be0);
    }
    __syncthreads();   // B3a: all HSR3/HD reads complete

    // publish m -> HSR3 (now R3)
#pragma unroll
    for (int at = 0; at < 4; at++)
#pragma unroll
        for (int r = 0; r < 4; r++)
            *reinterpret_cast<ushort_t*>(reinterpret_cast<char*>(HSR3) +
                (woff[r] + at * 4096)) = f2bf(m_acc[at][r]);
    __syncthreads();   // B3b

    // ---- message blocks ----
    for (int i = 0; i < NBLOCK; i++) {
        const ushort_t* Wm = Wt_msg  + i * 16384;
        const ushort_t* Wg = Wt_gate + i * 16384;
        float* aggp = agg + (size_t)i * N_ATOMS * HID;
        // P1: msg + gate GEMMs; epilogue -> M2T (transposed, b64-packed)
        {
            float bm = b_msg[i * HID + colM];
            f32x4 am_[4], ag_[4];
#pragma unroll
            for (int at = 0; at < 4; at++) {
                am_[at] = (f32x4){0.f, 0.f, 0.f, 0.f};
                ag_[at] = (f32x4){0.f, 0.f, 0.f, 0.f};
            }
#pragma unroll
            for (int ks = 0; ks < 4; ks++) {
                short8 Bm = ldB(Wm, colM, 128, ks * 32 + lk8);
                short8 Bg = ldB(Wg, colM, 128, ks * 32 + lk8);
                int lA = laneA ^ (ks * 64);
#pragma unroll
                for (int at = 0; at < 4; at++) {
                    short8 Am = *reinterpret_cast<const short8*>(
                        reinterpret_cast<const char*>(HSR3) + (lA + at * 4096));
                    short8 Ag = *reinterpret_cast<const short8*>(
                        reinterpret_cast<const char*>(R2) + (lA + at * 4096));
                    am_[at] = MFMA(Am, Bm, am_[at]);
                    ag_[at] = MFMA(Ag, Bg, ag_[at]);
                }
            }
#pragma unroll
            for (int at = 0; at < 4; at++) {
                float m2v[4];
#pragma unroll
                for (int r = 0; r < 4; r++) {
                    float m2 = silu(am_[at][r] + bm) * ag_[at][r];
                    m2v[r] = m2;
                    m_acc[at][r] += m2;
                }
                unsigned int plo = pkbf(m2v[0], m2v[1]);
                unsigned int phi = pkbf(m2v[2], m2v[3]);
                ull_t pk = ((ull_t)phi << 32) | plo;
                int addr = (colM * 128 + (at * 16 + g4 * 4) * 2) ^ ((colM & 7) << 4);
                *reinterpret_cast<ull_t*>(reinterpret_cast<char*>(M2T) + addr) = pk;
            }
        }
        __syncthreads();   // Ba: M2T complete; all R3/R2 reads done

        // P2: segment sum via MFMA: agg[run][c] = sum_e S[run][e] * m2[e][c]
        {
            int nruns = sm_nruns;
            short8 Bm2[2];
#pragma unroll
            for (int ks = 0; ks < 2; ks++) {
                int addr = (colM * 128 + (ks * 32 + lk8) * 2) ^ ((colM & 7) << 4);
                Bm2[ks] = *reinterpret_cast<const short8*>(
                    reinterpret_cast<const char*>(M2T) + addr);
            }
            for (int rt = 0; rt * 16 < nruns; rt++) {
                int tv = l15 + rt * 16;       // run this lane's A-row represents
                short8 SA[2];
#pragma unroll
                for (int ks = 0; ks < 2; ks++) {
                    ull_t rid8 = *reinterpret_cast<const ull_t*>(sm_runid8 + ks * 32 + lk8);
                    unsigned int rlo = (unsigned int)rid8;
                    unsigned int rhi = (unsigned int)(rid8 >> 32);
                    union { unsigned int u[4]; short8 s8; } sb;
#pragma unroll
                    for (int q = 0; q < 2; q++) {
                        unsigned int rr = q ? rhi : rlo;
                        unsigned int w0 = 0, w1 = 0;
                        if ((int)((rr >>  0) & 255) == tv) w0 |= 0x3F80u;
                        if ((int)((rr >>  8) & 255) == tv) w0 |= 0x3F800000u;
                        if ((int)((rr >> 16) & 255) == tv) w1 |= 0x3F80u;
                        if ((int)((rr >> 24) & 255) == tv) w1 |= 0x3F800000u;
                        sb.u[q * 2]     = w0;
                        sb.u[q * 2 + 1] = w1;
                    }
                    SA[ks] = sb.s8;
                }
                f32x4 acc0 = {0.f, 0.f, 0.f, 0.f};
                acc0 = MFMA(SA[0], Bm2[0], acc0);
                acc0 = MFMA(SA[1], Bm2[1], acc0);
#pragma unroll
                for (int r = 0; r < 4; r++) {
                    int run = rt * 16 + g4 * 4 + r;
                    if (run < nruns) {
                        int d = sm_slotdst[run];
                        atomicAdd(&aggp[(size_t)d * HID + colM], acc0[r]);
                    }
                }
            }
        }

        // publish updated m (R3; reads of old R3 finished at Ba)
        if (i < NBLOCK - 1) {
#pragma unroll
            for (int at = 0; at < 4; at++)
#pragma unroll
                for (int r = 0; r < 4; r++)
                    *reinterpret_cast<ushort_t*>(reinterpret_cast<char*>(HSR3) +
                        (woff[r] + at * 4096)) = f2bf(m_acc[at][r]);
        }
        __syncthreads();   // Bb: R3 ready, M2T free
    }

    // ---- force: f_e = m . W_force ; run-aggregated outF[dst] += f_e * unit ----
    {
        float wf0 = W_force[colM];
#pragma unroll
        for (int at = 0; at < 4; at++)
#pragma unroll
            for (int r = 0; r < 4; r++) {
                float part = m_acc[at][r] * wf0;
                part += __shfl_xor(part, 1, 64);
                part += __shfl_xor(part, 2, 64);
                part += __shfl_xor(part, 4, 64);
                part += __shfl_xor(part, 8, 64);
                if (l15 == 0)
                    atomicAdd(&sm_f[at * 16 + g4 * 4 + r], part);
            }
        __syncthreads();
        if (t < ETILE) {
            int e = t;
            int d = sm_dst[e];
            if (e == 0 || sm_dst[e - 1] != d) {
                float fx = 0.f, fy = 0.f, fz = 0.f;
                int j = e;
                do {
                    float f = sm_f[j];
                    fx += f * sm_unit[j][0];
                    fy += f * sm_unit[j][1];
                    fz += f * sm_unit[j][2];
                    j++;
                } while (j < ETILE && sm_dst[j] == d);
                atomicAdd(&outF[d * 3 + 0], fx);
                atomicAdd(&outF[d * 3 + 1], fy);
                atomicAdd(&outF[d * 3 + 2], fz);
            }
        }
    }
}

// ---- Atom-side (MFMA), 32-atom tiles: h = h0 + sum_i silu(agg_i @ W_upd_i + b);
//      out = h @ W_atom + b ----
__global__ __launch_bounds__(256)
void k_atom2(const float* __restrict__ agg,
             const ushort_t* __restrict__ Wt_upd,    // [3][128 col][128 k]
             const float* __restrict__ b_upd,
             const ushort_t* __restrict__ Wt_atom,   // [128 col(pad)][128 k]
             const float* __restrict__ b_atom,
             const ushort_t* __restrict__ h_bf,
             float* __restrict__ out) {
    __shared__ ushort_t RA[32 * HID];   // 8 KB staged A tile

    const int t    = threadIdx.x;
    const int lane = t & 63;
    const int wave = t >> 6;
    const int l15  = lane & 15;
    const int lk8  = 8 * (lane >> 4);
    const int colw = wave * 32;
    const int n0   = blockIdx.x * 32;

    const int laneA = l15 * 256 + ((lk8 * 2) ^ ((l15 & 7) << 4));
    int woff[2][4];
#pragma unroll
    for (int nt = 0; nt < 2; nt++)
#pragma unroll
        for (int r = 0; r < 4; r++) {
            int row = (lane >> 4) * 4 + r;
            woff[nt][r] = row * 256 + (((colw + nt * 16 + l15) * 2) ^ ((row & 7) << 4));
        }

    // h0 in C-layout f32 regs
    float h_acc[2][2][4];
#pragma unroll
    for (int at = 0; at < 2; at++)
#pragma unroll
        for (int nt = 0; nt < 2; nt++)
#pragma unroll
            for (int r = 0; r < 4; r++) {
                int row = at * 16 + (lane >> 4) * 4 + r;
                h_acc[at][nt][r] = bf2f(h_bf[(size_t)(n0 + row) * HID + colw + nt * 16 + l15]);
            }

    for (int i = 0; i < NBLOCK; i++) {
        // stage agg_i tile -> RA (f32 -> bf16, swizzled); coalesced f32x4 loads
        const float* ap = agg + (size_t)i * N_ATOMS * HID + (size_t)n0 * HID;
#pragma unroll
        for (int it = 0; it < 4; it++) {
            int u = it * 256 + t;
            int row = u >> 5, p = u & 31;
            f32x4 v = *reinterpret_cast<const f32x4*>(ap + (size_t)row * HID + 4 * p);
            unsigned int pk0 = pkbf(v[0], v[1]);
            unsigned int pk1 = pkbf(v[2], v[3]);
            int off = (row * 256 + 8 * p) ^ ((row & 7) << 4);
            *reinterpret_cast<unsigned int*>(reinterpret_cast<char*>(RA) + off)     = pk0;
            *reinterpret_cast<unsigned int*>(reinterpret_cast<char*>(RA) + off + 4) = pk1;
        }
        __syncthreads();

        const ushort_t* Wu = Wt_upd + i * 16384;
        float bu0 = b_upd[i * HID + colw + l15];
        float bu1 = b_upd[i * HID + colw + 16 + l15];
        f32x4 am[2][2];
#pragma unroll
        for (int at = 0; at < 2; at++)
#pragma unroll
            for (int nt = 0; nt < 2; nt++)
                am[at][nt] = (f32x4){0.f, 0.f, 0.f, 0.f};
#pragma unroll
        for (int ks = 0; ks < 4; ks++) {
            short8 B0 = ldB(Wu, colw + l15,      128, ks * 32 + lk8);
            short8 B1 = ldB(Wu, colw + 16 + l15, 128, ks * 32 + lk8);
            int lA = laneA ^ (ks * 64);
#pragma unroll
            for (int at = 0; at < 2; at++) {
                short8 A = *reinterpret_cast<const short8*>(
                    reinterpret_cast<const char*>(RA) + (lA + at * 4096));
                am[at][0] = MFMA(A, B0, am[at][0]);
                am[at][1] = MFMA(A, B1, am[at][1]);
            }
        }
#pragma unroll
        for (int at = 0; at < 2; at++)
#pragma unroll
            for (int r = 0; r < 4; r++) {
                h_acc[at][0][r] += silu(am[at][0][r] + bu0);
                h_acc[at][1][r] += silu(am[at][1][r] + bu1);
            }
        __syncthreads();
    }

    // publish h -> RA (bf16), head GEMM
#pragma unroll
    for (int at = 0; at < 2; at++)
#pragma unroll
        for (int nt = 0; nt < 2; nt++)
#pragma unroll
            for (int r = 0; r < 4; r++)
                *reinterpret_cast<ushort_t*>(reinterpret_cast<char*>(RA) +
                    (woff[nt][r] + at * 4096)) = f2bf(h_acc[at][nt][r]);
    __syncthreads();

    {
        f32x4 am[2][2];
#pragma unroll
        for (int at = 0; at < 2; at++)
#pragma unroll
            for (int nt = 0; nt < 2; nt++)
                am[at][nt] = (f32x4){0.f, 0.f, 0.f, 0.f};
#pragma unroll
        for (int ks = 0; ks < 4; ks++) {
            short8 B0 = ldB(Wt_atom, colw + l15,      128, ks * 32 + lk8);
            short8 B1 = ldB(Wt_atom, colw + 16 + l15, 128, ks * 32 + lk8);
            int lA = laneA ^ (ks * 64);
#pragma unroll
            for (int at = 0; at < 2; at++) {
                short8 A = *reinterpret_cast<const short8*>(
                    reinterpret_cast<const char*>(RA) + (lA + at * 4096));
                am[at][0] = MFMA(A, B0, am[at][0]);
                am[at][1] = MFMA(A, B1, am[at][1]);
            }
        }
        int col0 = colw + l15;
        int col1 = colw + 16 + l15;
        float ba0 = (col0 < MAXZ) ? b_atom[col0] : 0.f;
        float ba1 = (col1 < MAXZ) ? b_atom[col1] : 0.f;
#pragma unroll
        for (int at = 0; at < 2; at++)
#pragma unroll
            for (int r = 0; r < 4; r++) {
                int row = n0 + at * 16 + (lane >> 4) * 4 + r;
                if (col0 < MAXZ)
                    out[(size_t)N_ATOMS * 3 + (size_t)row * MAXZ + col0] = am[at][0][r] + ba0;
                if (col1 < MAXZ)
                    out[(size_t)N_ATOMS * 3 + (size_t)row * MAXZ + col1] = am[at][1][r] + ba1;
            }
    }
}

extern "C" void kernel_launch(void* const* d_in, const int* in_sizes, int n_in,
                              void* d_out, int out_size, void* d_ws, size_t ws_size,
                              hipStream_t stream) {
    const float* z         = (const float*)d_in[0];
    const float* frac      = (const float*)d_in[1];
    const int*   types     = (const int*)d_in[2];
    const float* lengths   = (const float*)d_in[4];
    const float* angles    = (const float*)d_in[5];
    const int*   edge_idx  = (const int*)d_in[6];
    const float* atom_emb  = (const float*)d_in[7];
    const float* W_in      = (const float*)d_in[8];
    const float* b_in      = (const float*)d_in[9];
    const float* W_rbf     = (const float*)d_in[10];
    const float* W_edge    = (const float*)d_in[11];
    const float* b_edge    = (const float*)d_in[12];
    const float* W_msg     = (const float*)d_in[13];
    const float* b_msg     = (const float*)d_in[14];
    const float* W_gate    = (const float*)d_in[15];
    const float* W_upd     = (const float*)d_in[16];
    const float* b_upd     = (const float*)d_in[17];
    const float* W_force   = (const float*)d_in[18];
    const float* W_atom    = (const float*)d_in[19];
    const float* b_atom    = (const float*)d_in[20];

    float* out = (float*)d_out;

    // workspace layout
    float* ws = (float*)d_ws;
    size_t off = 0;
    float* cart = ws + off; off += (size_t)N_ATOMS * 3;
    float* agg  = ws + off; off += (size_t)NBLOCK * N_ATOMS * HID;
    float* embW = ws + off; off += MAXZ * HID;
    float* zW   = ws + off; off += N_CRYST * HID;
    float* T    = ws + off; off += (size_t)(TABN + 2) * HID;
    int* cnt    = (int*)(ws + off); off += N_ATOMS;
    int* cursor = (int*)(ws + off); off += N_ATOMS;
    int* perm   = (int*)(ws + off); off += N_EDGES;
    off = (off + 7) & ~(size_t)7;
    ushort_t* ub = (ushort_t*)(ws + off);
    size_t uoff = 0;
    ushort_t* h_bf    = ub + uoff; uoff += (size_t)N_ATOMS * HID;
    ushort_t* Wt_edge = ub + uoff; uoff += 128 * 384;
    ushort_t* Wt_msg  = ub + uoff; uoff += 3 * 128 * 128;
    ushort_t* Wt_gate = ub + uoff; uoff += 3 * 128 * 128;
    ushort_t* Wt_upd  = ub + uoff; uoff += 3 * 128 * 128;
    ushort_t* Wt_atom = ub + uoff; uoff += 128 * 128;

    // 1) zero-init (out force region, agg, cnt)
    k_init<<<(NBLOCK * N_ATOMS * HID + 255) / 256, 256, 0, stream>>>(out, agg, cnt);

    // 2) fused preprocessing: hist | cart | table | weight prep | embW | zW
    k_fuse0<<<F0_ZW, 256, 0, stream>>>(edge_idx, cnt, lengths, angles, frac, cart,
                                       W_rbf, T,
                                       W_edge, W_msg, W_gate, W_upd, W_atom,
                                       Wt_edge, Wt_msg, Wt_gate, Wt_upd, Wt_atom,
                                       atom_emb, W_in, b_in, embW, z, zW);

    // 3) scan
    k_scan<<<1, 256, 0, stream>>>(cnt, cursor);

    // 4) fused scatter + h0
    k_fuse1<<<1280 + (N_ATOMS * HID) / 256, 256, 0, stream>>>(edge_idx, cursor, perm,
                                                              types, embW, zW, h_bf);

    // 5) edge pipeline
    k_edges<<<N_EDGES / ETILE, 512, 0, stream>>>(perm, edge_idx, cart, T, h_bf,
                                                 Wt_edge, b_edge,
                                                 Wt_msg, b_msg, Wt_gate, W_force,
                                                 agg, out);

    // 6) atom-side update + head
    k_atom2<<<N_ATOMS / 32, 256, 0, stream>>>(agg, Wt_upd, b_upd, Wt_atom, b_atom,
                                              h_bf, out);
}

// Round 14
// 365.091 us; speedup vs baseline: 1.2333x; 1.0051x over previous
//
#include <hip/hip_runtime.h>
#include <hip/hip_bf16.h>

#define N_CRYST 256
#define ATOMS_PER 64
#define N_ATOMS (N_CRYST * ATOMS_PER)   // 16384
#define N_EDGES (N_ATOMS * 20)          // 327680
#define HID 128
#define LAT 256
#define NRAD 128
#define NBLOCK 3
#define MAXZ 100
#define CUTOFF 6.0f
#define PI_F 3.14159265358979323846f
#define ETILE 64
#define TABN 2048                        // table intervals over [0, CUTOFF]

typedef unsigned short ushort_t;
typedef unsigned char uchar_t;
typedef unsigned long long ull_t;
typedef __attribute__((ext_vector_type(8))) short short8;
typedef __attribute__((ext_vector_type(4))) float f32x4;

__device__ __forceinline__ float fexp2(float x) {
    float r; asm("v_exp_f32 %0, %1" : "=v"(r) : "v"(x)); return r;
}
__device__ __forceinline__ float frcp(float x) {
    float r; asm("v_rcp_f32 %0, %1" : "=v"(r) : "v"(x)); return r;
}
// silu(x) = x / (1 + exp(-x)) = x * rcp(1 + 2^(-x*log2e))
__device__ __forceinline__ float silu(float x) {
    return x * frcp(1.0f + fexp2(x * -1.44269504f));
}

__device__ __forceinline__ ushort_t f2bf(float v) {          // fast RNE (finite inputs)
    unsigned int u = __float_as_uint(v);
    return (ushort_t)((u + 0x7FFF + ((u >> 16) & 1)) >> 16);
}
__device__ __forceinline__ float bf2f(ushort_t u) {
    return __uint_as_float((unsigned int)u << 16);
}
// packed bf16 convert: dst.lo = bf16(lo), dst.hi = bf16(hi) — 1 VALU instr
__device__ __forceinline__ unsigned int pkbf(float lo, float hi) {
    unsigned int r;
    asm("v_cvt_pk_bf16_f32 %0, %1, %2" : "=v"(r) : "v"(lo), "v"(hi));
    return r;
}

__device__ __forceinline__ f32x4 MFMA(short8 a, short8 b, f32x4 c) {
    return __builtin_amdgcn_mfma_f32_16x16x32_bf16(a, b, c, 0, 0, 0);
}

// swizzled byte offset for [64][128] bf16 LDS tiles: (row*256 + col*2) ^ ((row&7)<<4)
__device__ __forceinline__ int swz(int row, int k) {
    return (row * 256 + k * 2) ^ ((row & 7) << 4);
}

__device__ __forceinline__ short8 ldB(const ushort_t* W, int col, int K, int k) {
    return *reinterpret_cast<const short8*>(W + (size_t)col * K + k);
}

// ---- fused zero-init: out force region, agg, cnt ----
__global__ void k_init(float* __restrict__ out, float* __restrict__ agg,
                       int* __restrict__ cnt) {
    int i = blockIdx.x * blockDim.x + threadIdx.x;
    if (i < N_ATOMS * 3) out[i] = 0.0f;
    if (i < N_ATOMS) cnt[i] = 0;
    if (i < NBLOCK * N_ATOMS * HID) agg[i] = 0.0f;
}

// ---- exclusive scan of 16384 counts (single block, 256 threads) ----
__global__ void k_scan(const int* __restrict__ cnt, int* __restrict__ cursor) {
    __shared__ int partial[256];
    int t = threadIdx.x;
    int base = t * (N_ATOMS / 256);
    int s = 0;
    for (int j = 0; j < N_ATOMS / 256; j++) s += cnt[base + j];
    partial[t] = s;
    __syncthreads();
    if (t == 0) {
        int run = 0;
        for (int i = 0; i < 256; i++) { int v = partial[i]; partial[i] = run; run += v; }
    }
    __syncthreads();
    int run = partial[t];
    for (int j = 0; j < N_ATOMS / 256; j++) {
        cursor[base + j] = run;
        run += cnt[base + j];
    }
}

// ---- fused preprocessing: hist | cart(+inline latt) | rbf_h table | weight prep | embW | zW ----
#define F0_HIST 1280
#define F0_CART (F0_HIST + 64)
#define F0_TAB  (F0_CART + 1025)
#define F0_PREP (F0_TAB + 192)
#define F0_EMBW (F0_PREP + 50)
#define F0_ZW   (F0_EMBW + 128)
__global__ void k_fuse0(const int* __restrict__ edge_index, int* __restrict__ cnt,
                        const float* __restrict__ lengths, const float* __restrict__ angles,
                        const float* __restrict__ frac, float* __restrict__ cart,
                        const float* __restrict__ W_rbf, float* __restrict__ T,
                        const float* __restrict__ W_edge, const float* __restrict__ W_msg,
                        const float* __restrict__ W_gate, const float* __restrict__ W_upd,
                        const float* __restrict__ W_atom,
                        ushort_t* __restrict__ Wt_edge, ushort_t* __restrict__ Wt_msg,
                        ushort_t* __restrict__ Wt_gate, ushort_t* __restrict__ Wt_upd,
                        ushort_t* __restrict__ Wt_atom,
                        const float* __restrict__ atom_emb, const float* __restrict__ W_in,
                        const float* __restrict__ b_in, float* __restrict__ embW,
                        const float* __restrict__ z, float* __restrict__ zW) {
    __shared__ float sh[512];
    int b = blockIdx.x, t = threadIdx.x;
    if (b < F0_HIST) {
        int e = b * 256 + t;
        atomicAdd(&cnt[edge_index[N_EDGES + e]], 1);
    } else if (b < F0_CART) {
        int n = (b - F0_HIST) * 256 + t;
        int c = n >> 6;   // crystal
        float a  = lengths[c * 3 + 0];
        float bb = lengths[c * 3 + 1];
        float cc = lengths[c * 3 + 2];
        float al = angles[c * 3 + 0] * (PI_F / 180.0f);
        float be = angles[c * 3 + 1] * (PI_F / 180.0f);
        float ga = angles[c * 3 + 2] * (PI_F / 180.0f);
        float cos_a = cosf(al), cos_b = cosf(be), cos_g = cosf(ga);
        float sin_a = sinf(al), sin_b = sinf(be);
        float val = (cos_a * cos_b - cos_g) / (sin_a * sin_b);
        val = fminf(1.0f, fmaxf(-1.0f, val));
        float gs = acosf(val);
        float L0 = a * sin_b, L2 = a * cos_b;
        float L3 = -bb * sin_a * cosf(gs), L4 = bb * sin_a * sinf(gs), L5 = bb * cos_a;
        float f0 = frac[n * 3 + 0], f1 = frac[n * 3 + 1], f2 = frac[n * 3 + 2];
        cart[n * 3 + 0] = f0 * L0 + f1 * L3;
        cart[n * 3 + 1] = f1 * L4;
        cart[n * 3 + 2] = f0 * L2 + f1 * L5 + f2 * cc;
    } else if (b < F0_TAB) {
        int half = t >> 7, c = t & 127;
        int j = (b - F0_CART) * 2 + half;   // 0..2049
        float d = (float)j * (CUTOFF / TABN);
        const float inv2w2 = 1.0f / (2.0f * (CUTOFF / NRAD) * (CUTOFF / NRAD));
        const float cstep = CUTOFF / (NRAD - 1);
        float x = fminf(1.0f, d * (1.0f / CUTOFF));
        float env = 0.5f * (cosf(PI_F * x) + 1.0f);
        float diff = d - (float)c * cstep;
        sh[half * 128 + c] = expf(-diff * diff * inv2w2) * env;
        __syncthreads();
        float acc = 0.0f;
#pragma unroll 8
        for (int k = 0; k < NRAD; k++) acc += sh[half * 128 + k] * W_rbf[k * HID + c];
        T[(size_t)j * HID + c] = acc;
    } else if (b < F0_PREP) {
        int i = (b - F0_TAB) * 256 + t;     // < 49152
        {
            int c = i / 384, k = i % 384;
            Wt_edge[(size_t)c * 384 + k] = f2bf(W_edge[k * 128 + c]);
        }
        {
            int blk = i >> 14, r = i & 16383;
            int c = r >> 7, k = r & 127;
            Wt_msg[blk * 16384 + c * 128 + k]  = f2bf(W_msg[blk * 16384 + k * 128 + c]);
            Wt_gate[blk * 16384 + c * 128 + k] = f2bf(W_gate[blk * 16384 + k * 128 + c]);
            Wt_upd[blk * 16384 + c * 128 + k]  = f2bf(W_upd[blk * 16384 + k * 128 + c]);
        }
        if (i < 128 * 128) {
            int c = i >> 7, k = i & 127;
            Wt_atom[c * 128 + k] = (c < MAXZ) ? f2bf(W_atom[k * MAXZ + c]) : (ushort_t)0;
        }
    } else if (b < F0_EMBW) {
        int half = t >> 7, c = t & 127;
        int zi = (b - F0_PREP) * 2 + half;  // 0..99
        sh[half * 128 + c] = atom_emb[zi * HID + c];
        __syncthreads();
        float acc = b_in[c];
#pragma unroll 8
        for (int k = 0; k < HID; k++) acc += sh[half * 128 + k] * W_in[k * HID + c];
        embW[zi * HID + c] = acc;
    } else {
        int half = t >> 7, c = t & 127;
        int bc = (b - F0_EMBW) * 2 + half;  // 0..255
        sh[half * 256 + c]       = z[bc * LAT + c];
        sh[half * 256 + 128 + c] = z[bc * LAT + 128 + c];
        __syncthreads();
        float acc = 0.f;
#pragma unroll 8
        for (int k = 0; k < LAT; k++) acc += sh[half * 256 + k] * W_in[(HID + k) * HID + c];
        zW[bc * HID + c] = acc;
    }
}

// ---- fused: scatter (needs scan) + h0 gather/silu ----
__global__ void k_fuse1(const int* __restrict__ edge_index,
                        int* __restrict__ cursor, int* __restrict__ perm,
                        const int* __restrict__ types,
                        const float* __restrict__ embW, const float* __restrict__ zW,
                        ushort_t* __restrict__ h_bf) {
    int b = blockIdx.x, t = threadIdx.x;
    if (b < 1280) {
        int e = b * 256 + t;
        int pos = atomicAdd(&cursor[edge_index[N_EDGES + e]], 1);
        perm[pos] = e;
    } else {
        int idx = (b - 1280) * 256 + t;
        int n = idx >> 7, c = idx & 127;
        float v = embW[types[n] * HID + c] + zW[(n >> 6) * HID + c];
        h_bf[idx] = f2bf(silu(v));
    }
}

// ---- Fused edge kernel: double-buffered m, wave-local M2T (1 barrier per msg block) ----
__global__ __launch_bounds__(512, 4)
void k_edges(const int* __restrict__ perm,
             const int* __restrict__ edge_index,
             const float* __restrict__ cart,
             const float* __restrict__ T,      // [TABN+2][HID] rbf_h table
             const ushort_t* __restrict__ h_bf,
             const ushort_t* __restrict__ Wt_edge,
             const float* __restrict__ b_edge,
             const ushort_t* __restrict__ Wt_msg,
             const float* __restrict__ b_msg,
             const ushort_t* __restrict__ Wt_gate,
             const float* __restrict__ W_force,
             float* __restrict__ agg,    // [NBLOCK][N_ATOMS][HID]
             float* __restrict__ outF)   // [N_ATOMS][3]
{
    __shared__ ushort_t R2[ETILE * HID];    // rbf_h (persists)
    __shared__ ushort_t HSR3[ETILE * HID];  // staged h_src, then m buffer B
    __shared__ ushort_t HD[ETILE * HID];    // staged h_dst, then M2T (wave-local)
    __shared__ ushort_t MB[ETILE * HID];    // m buffer A
    __shared__ int   sm_dst[ETILE];
    __shared__ float sm_unit[ETILE][3];
    __shared__ float sm_d[ETILE];
    __shared__ float sm_f[ETILE];
    __shared__ uchar_t sm_runid8[ETILE];
    __shared__ int   sm_slotdst[ETILE];
    __shared__ int   sm_nruns;
    ushort_t* M2T = HD;    // HD is dead after GEMM2+B3

    const int t    = threadIdx.x;
    const int lane = t & 63;
    const int wave = t >> 6;             // 0..7
    const int l15  = lane & 15;
    const int g4   = lane >> 4;          // 0..3
    const int lk8  = 8 * g4;
    const int colw = wave * 16;          // this wave's 16 output cols
    const int e0   = blockIdx.x * ETILE;

    // per-lane static LDS addressing bases
    const int laneA = l15 * 256 + ((lk8 * 2) ^ ((l15 & 7) << 4));   // A-frag read base
    const int colM  = colw + l15;                                    // this lane's col
    int woff[4];                                                     // m C-write bases
#pragma unroll
    for (int r = 0; r < 4; r++) {
        int row = g4 * 4 + r;
        woff[r] = row * 256 + ((colM * 2) ^ ((row & 7) << 4));
    }

    // ---- Phase A: geometry ----
    if (t < ETILE) {
        int e = t;
        int eid = perm[e0 + e];
        int s = edge_index[eid];
        int d = edge_index[N_EDGES + eid];
        sm_dst[e] = d;
        float vx = cart[d * 3 + 0] - cart[s * 3 + 0];
        float vy = cart[d * 3 + 1] - cart[s * 3 + 1];
        float vz = cart[d * 3 + 2] - cart[s * 3 + 2];
        float dist = sqrtf(vx * vx + vy * vy + vz * vz) + 1e-8f;
        sm_d[e] = dist;
        float di = 1.0f / dist;
        sm_unit[e][0] = vx * di; sm_unit[e][1] = vy * di; sm_unit[e][2] = vz * di;
        sm_f[e] = 0.0f;
    }
    __syncthreads();   // B1

    // ---- issue h_src/h_dst tile loads (latency hidden under lerp phase) ----
    short8 hs[2], hd[2];
    int stoff[2];
#pragma unroll
    for (int p = 0; p < 2; p++) {
        int u   = p * 512 + t;       // 0..1023 = 64 rows x 16 chunks
        int row = u >> 4;
        int seg = u & 15;
        int eid = perm[e0 + row];
        int s = edge_index[eid];
        int d = edge_index[N_EDGES + eid];
        hs[p] = *reinterpret_cast<const short8*>(h_bf + (size_t)s * HID + seg * 8);
        hd[p] = *reinterpret_cast<const short8*>(h_bf + (size_t)d * HID + seg * 8);
        stoff[p] = swz(row, seg * 8);
    }

    // ---- run ids over sorted dst (wave 0, ballot) ----
    if (wave == 0) {
        int e = lane;
        int d = sm_dst[e];
        int prev = (e == 0) ? -1 : sm_dst[e - 1];
        ull_t mask = __ballot(d != prev);
        int rid = __popcll(mask & ((2ull << e) - 1)) - 1;
        sm_runid8[e] = (uchar_t)rid;
        if (d != prev) sm_slotdst[rid] = d;
        if (e == 0) sm_nruns = __popcll(mask);
    }

    // ---- Phase B: rbf_h via table lerp -> R2 ; write staged h tiles ----
    {
#pragma unroll
        for (int it = 0; it < 4; it++) {
            int u = it * 512 + t;          // 2048 units = 64 edges x 32 col-quads
            int e = u >> 5;
            int p = u & 31;                // cols 4p..4p+3
            float idxf = sm_d[e] * (TABN / CUTOFF);
            idxf = fminf(idxf, (float)TABN);
            int j = (int)idxf;
            float fr = idxf - (float)j;
            f32x4 lo = *reinterpret_cast<const f32x4*>(T + (size_t)j * HID + 4 * p);
            f32x4 hi = *reinterpret_cast<const f32x4*>(T + (size_t)(j + 1) * HID + 4 * p);
            float v0 = lo[0] + fr * (hi[0] - lo[0]);
            float v1 = lo[1] + fr * (hi[1] - lo[1]);
            float v2 = lo[2] + fr * (hi[2] - lo[2]);
            float v3 = lo[3] + fr * (hi[3] - lo[3]);
            unsigned int pk0 = pkbf(v0, v1);
            unsigned int pk1 = pkbf(v2, v3);
            int off = (e * 256 + 8 * p) ^ ((e & 7) << 4);
            *reinterpret_cast<unsigned int*>(reinterpret_cast<char*>(R2) + off)     = pk0;
            *reinterpret_cast<unsigned int*>(reinterpret_cast<char*>(R2) + off + 4) = pk1;
        }
        // staged h -> LDS (vmcnt waits inserted by compiler)
#pragma unroll
        for (int p = 0; p < 2; p++) {
            *reinterpret_cast<short8*>(reinterpret_cast<char*>(HSR3) + stoff[p]) = hs[p];
            *reinterpret_cast<short8*>(reinterpret_cast<char*>(HD)   + stoff[p]) = hd[p];
        }
    }
    __syncthreads();   // B2

    // ---- GEMM2 (all-LDS A): m0 = silu([h_src|h_dst|rbf_h] @ W_edge + b_edge) -> MB ----
    float m_acc[4][4];     // [at][r]
    {
        f32x4 am[4];
#pragma unroll
        for (int at = 0; at < 4; at++) am[at] = (f32x4){0.f, 0.f, 0.f, 0.f};
        const ushort_t* segp[3] = {HSR3, HD, R2};
        __builtin_amdgcn_s_setprio(1);
#pragma unroll
        for (int seg = 0; seg < 3; seg++) {
#pragma unroll
            for (int ks = 0; ks < 4; ks++) {
                int kg = seg * 128 + ks * 32 + lk8;
                short8 B0 = ldB(Wt_edge, colM, 384, kg);
                int lA = laneA ^ (ks * 64);
#pragma unroll
                for (int at = 0; at < 4; at++) {
                    short8 A = *reinterpret_cast<const short8*>(
                        reinterpret_cast<const char*>(segp[seg]) + (lA + at * 4096));
                    am[at] = MFMA(A, B0, am[at]);
                }
            }
        }
        __builtin_amdgcn_s_setprio(0);
        float be0 = b_edge[colM];
#pragma unroll
        for (int at = 0; at < 4; at++)
#pragma unroll
            for (int r = 0; r < 4; r++)
                m_acc[at][r] = silu(am[at][r] + be0);
        // publish m0 -> MB (own cols; MB untouched before B3)
#pragma unroll
        for (int at = 0; at < 4; at++)
#pragma unroll
            for (int r = 0; r < 4; r++)
                *reinterpret_cast<ushort_t*>(reinterpret_cast<char*>(MB) +
                    (woff[r] + at * 4096)) = f2bf(m_acc[at][r]);
    }
    __syncthreads();   // B3: HSR3/HD reads done; MB (m0) visible

    // ---- message blocks: P1 (GEMMs -> M2T wave-local + m-next) ; P2 (segsum) ; 1 barrier ----
#pragma unroll
    for (int i = 0; i < NBLOCK; i++) {
        const ushort_t* mcur = (i == 1) ? HSR3 : MB;   // compile-time (unrolled)
        ushort_t*       mnxt = (i == 0) ? HSR3 : MB;
        const ushort_t* Wm = Wt_msg  + i * 16384;
        const ushort_t* Wg = Wt_gate + i * 16384;
        float* aggp = agg + (size_t)i * N_ATOMS * HID;
        // P1: msg + gate GEMMs; epilogue -> M2T (wave-local) + m-next (own cols)
        {
            float bm = b_msg[i * HID + colM];
            f32x4 am_[4], ag_[4];
#pragma unroll
            for (int at = 0; at < 4; at++) {
                am_[at] = (f32x4){0.f, 0.f, 0.f, 0.f};
                ag_[at] = (f32x4){0.f, 0.f, 0.f, 0.f};
            }
            __builtin_amdgcn_s_setprio(1);
#pragma unroll
            for (int ks = 0; ks < 4; ks++) {
                short8 Bm = ldB(Wm, colM, 128, ks * 32 + lk8);
                short8 Bg = ldB(Wg, colM, 128, ks * 32 + lk8);
                int lA = laneA ^ (ks * 64);
#pragma unroll
                for (int at = 0; at < 4; at++) {
                    short8 Am = *reinterpret_cast<const short8*>(
                        reinterpret_cast<const char*>(mcur) + (lA + at * 4096));
                    short8 Ag = *reinterpret_cast<const short8*>(
                        reinterpret_cast<const char*>(R2) + (lA + at * 4096));
                    am_[at] = MFMA(Am, Bm, am_[at]);
                    ag_[at] = MFMA(Ag, Bg, ag_[at]);
                }
            }
            __builtin_amdgcn_s_setprio(0);
#pragma unroll
            for (int at = 0; at < 4; at++) {
                float m2v[4];
#pragma unroll
                for (int r = 0; r < 4; r++) {
                    float m2 = silu(am_[at][r] + bm) * ag_[at][r];
                    m2v[r] = m2;
                    m_acc[at][r] += m2;
                }
                unsigned int plo = pkbf(m2v[0], m2v[1]);
                unsigned int phi = pkbf(m2v[2], m2v[3]);
                ull_t pk = ((ull_t)phi << 32) | plo;
                int addr = (colM * 128 + (at * 16 + g4 * 4) * 2) ^ ((colM & 7) << 4);
                *reinterpret_cast<ull_t*>(reinterpret_cast<char*>(M2T) + addr) = pk;
                if (i < NBLOCK - 1) {
#pragma unroll
                    for (int r = 0; r < 4; r++)
                        *reinterpret_cast<ushort_t*>(reinterpret_cast<char*>(mnxt) +
                            (woff[r] + at * 4096)) = f2bf(m_acc[at][r]);
                }
            }
        }

        // P2: segment sum via MFMA (M2T reads are wave-local; no barrier needed)
        {
            int nruns = sm_nruns;
            short8 Bm2[2];
#pragma unroll
            for (int ks = 0; ks < 2; ks++) {
                int addr = (colM * 128 + (ks * 32 + lk8) * 2) ^ ((colM & 7) << 4);
                Bm2[ks] = *reinterpret_cast<const short8*>(
                    reinterpret_cast<const char*>(M2T) + addr);
            }
            for (int rt = 0; rt * 16 < nruns; rt++) {
                int tv = l15 + rt * 16;       // run this lane's A-row represents
                short8 SA[2];
#pragma unroll
                for (int ks = 0; ks < 2; ks++) {
                    ull_t rid8 = *reinterpret_cast<const ull_t*>(sm_runid8 + ks * 32 + lk8);
                    unsigned int rlo = (unsigned int)rid8;
                    unsigned int rhi = (unsigned int)(rid8 >> 32);
                    union { unsigned int u[4]; short8 s8; } sb;
#pragma unroll
                    for (int q = 0; q < 2; q++) {
                        unsigned int rr = q ? rhi : rlo;
                        unsigned int w0 = 0, w1 = 0;
                        if ((int)((rr >>  0) & 255) == tv) w0 |= 0x3F80u;
                        if ((int)((rr >>  8) & 255) == tv) w0 |= 0x3F800000u;
                        if ((int)((rr >> 16) & 255) == tv) w1 |= 0x3F80u;
                        if ((int)((rr >> 24) & 255) == tv) w1 |= 0x3F800000u;
                        sb.u[q * 2]     = w0;
                        sb.u[q * 2 + 1] = w1;
                    }
                    SA[ks] = sb.s8;
                }
                f32x4 acc0 = {0.f, 0.f, 0.f, 0.f};
                acc0 = MFMA(SA[0], Bm2[0], acc0);
                acc0 = MFMA(SA[1], Bm2[1], acc0);
#pragma unroll
                for (int r = 0; r < 4; r++) {
                    int run = rt * 16 + g4 * 4 + r;
                    if (run < nruns) {
                        int d = sm_slotdst[run];
                        atomicAdd(&aggp[(size_t)d * HID + colM], acc0[r]);
                    }
                }
            }
        }

        if (i < NBLOCK - 1) __syncthreads();   // m-next visible for next P1's A-reads
    }

    // ---- force: f_e = m . W_force ; run-aggregated outF[dst] += f_e * unit ----
    {
        float wf0 = W_force[colM];
#pragma unroll
        for (int at = 0; at < 4; at++)
#pragma unroll
            for (int r = 0; r < 4; r++) {
                float part = m_acc[at][r] * wf0;
                part += __shfl_xor(part, 1, 64);
                part += __shfl_xor(part, 2, 64);
                part += __shfl_xor(part, 4, 64);
                part += __shfl_xor(part, 8, 64);
                if (l15 == 0)
                    atomicAdd(&sm_f[at * 16 + g4 * 4 + r], part);
            }
        __syncthreads();
        if (t < ETILE) {
            int e = t;
            int d = sm_dst[e];
            if (e == 0 || sm_dst[e - 1] != d) {
                float fx = 0.f, fy = 0.f, fz = 0.f;
                int j = e;
                do {
                    float f = sm_f[j];
                    fx += f * sm_unit[j][0];
                    fy += f * sm_unit[j][1];
                    fz += f * sm_unit[j][2];
                    j++;
                } while (j < ETILE && sm_dst[j] == d);
                atomicAdd(&outF[d * 3 + 0], fx);
                atomicAdd(&outF[d * 3 + 1], fy);
                atomicAdd(&outF[d * 3 + 2], fz);
            }
        }
    }
}

// ---- Atom-side (MFMA), 32-atom tiles ----
__global__ __launch_bounds__(256)
void k_atom2(const float* __restrict__ agg,
             const ushort_t* __restrict__ Wt_upd,    // [3][128 col][128 k]
             const float* __restrict__ b_upd,
             const ushort_t* __restrict__ Wt_atom,   // [128 col(pad)][128 k]
             const float* __restrict__ b_atom,
             const ushort_t* __restrict__ h_bf,
             float* __restrict__ out) {
    __shared__ ushort_t RA[32 * HID];   // 8 KB staged A tile

    const int t    = threadIdx.x;
    const int lane = t & 63;
    const int wave = t >> 6;
    const int l15  = lane & 15;
    const int lk8  = 8 * (lane >> 4);
    const int colw = wave * 32;
    const int n0   = blockIdx.x * 32;

    const int laneA = l15 * 256 + ((lk8 * 2) ^ ((l15 & 7) << 4));
    int woff[2][4];
#pragma unroll
    for (int nt = 0; nt < 2; nt++)
#pragma unroll
        for (int r = 0; r < 4; r++) {
            int row = (lane >> 4) * 4 + r;
            woff[nt][r] = row * 256 + (((colw + nt * 16 + l15) * 2) ^ ((row & 7) << 4));
        }

    // h0 in C-layout f32 regs
    float h_acc[2][2][4];
#pragma unroll
    for (int at = 0; at < 2; at++)
#pragma unroll
        for (int nt = 0; nt < 2; nt++)
#pragma unroll
            for (int r = 0; r < 4; r++) {
                int row = at * 16 + (lane >> 4) * 4 + r;
                h_acc[at][nt][r] = bf2f(h_bf[(size_t)(n0 + row) * HID + colw + nt * 16 + l15]);
            }

    for (int i = 0; i < NBLOCK; i++) {
        // stage agg_i tile -> RA (f32 -> bf16, swizzled); coalesced f32x4 loads
        const float* ap = agg + (size_t)i * N_ATOMS * HID + (size_t)n0 * HID;
#pragma unroll
        for (int it = 0; it < 4; it++) {
            int u = it * 256 + t;
            int row = u >> 5, p = u & 31;
            f32x4 v = *reinterpret_cast<const f32x4*>(ap + (size_t)row * HID + 4 * p);
            unsigned int pk0 = pkbf(v[0], v[1]);
            unsigned int pk1 = pkbf(v[2], v[3]);
            int off = (row * 256 + 8 * p) ^ ((row & 7) << 4);
            *reinterpret_cast<unsigned int*>(reinterpret_cast<char*>(RA) + off)     = pk0;
            *reinterpret_cast<unsigned int*>(reinterpret_cast<char*>(RA) + off + 4) = pk1;
        }
        __syncthreads();

        const ushort_t* Wu = Wt_upd + i * 16384;
        float bu0 = b_upd[i * HID + colw + l15];
        float bu1 = b_upd[i * HID + colw + 16 + l15];
        f32x4 am[2][2];
#pragma unroll
        for (int at = 0; at < 2; at++)
#pragma unroll
            for (int nt = 0; nt < 2; nt++)
                am[at][nt] = (f32x4){0.f, 0.f, 0.f, 0.f};
#pragma unroll
        for (int ks = 0; ks < 4; ks++) {
            short8 B0 = ldB(Wu, colw + l15,      128, ks * 32 + lk8);
            short8 B1 = ldB(Wu, colw + 16 + l15, 128, ks * 32 + lk8);
            int lA = laneA ^ (ks * 64);
#pragma unroll
            for (int at = 0; at < 2; at++) {
                short8 A = *reinterpret_cast<const short8*>(
                    reinterpret_cast<const char*>(RA) + (lA + at * 4096));
                am[at][0] = MFMA(A, B0, am[at][0]);
                am[at][1] = MFMA(A, B1, am[at][1]);
            }
        }
#pragma unroll
        for (int at = 0; at < 2; at++)
#pragma unroll
            for (int r = 0; r < 4; r++) {
                h_acc[at][0][r] += silu(am[at][0][r] + bu0);
                h_acc[at][1][r] += silu(am[at][1][r] + bu1);
            }
        __syncthreads();
    }

    // publish h -> RA (bf16), head GEMM
#pragma unroll
    for (int at = 0; at < 2; at++)
#pragma unroll
        for (int nt = 0; nt < 2; nt++)
#pragma unroll
            for (int r = 0; r < 4; r++)
                *reinterpret_cast<ushort_t*>(reinterpret_cast<char*>(RA) +
                    (woff[nt][r] + at * 4096)) = f2bf(h_acc[at][nt][r]);
    __syncthreads();

    {
        f32x4 am[2][2];
#pragma unroll
        for (int at = 0; at < 2; at++)
#pragma unroll
            for (int nt = 0; nt < 2; nt++)
                am[at][nt] = (f32x4){0.f, 0.f, 0.f, 0.f};
#pragma unroll
        for (int ks = 0; ks < 4; ks++) {
            short8 B0 = ldB(Wt_atom, colw + l15,      128, ks * 32 + lk8);
            short8 B1 = ldB(Wt_atom, colw + 16 + l15, 128, ks * 32 + lk8);
            int lA = laneA ^ (ks * 64);
#pragma unroll
            for (int at = 0; at < 2; at++) {
                short8 A = *reinterpret_cast<const short8*>(
                    reinterpret_cast<const char*>(RA) + (lA + at * 4096));
                am[at][0] = MFMA(A, B0, am[at][0]);
                am[at][1] = MFMA(A, B1, am[at][1]);
            }
        }
        int col0 = colw + l15;
        int col1 = colw + 16 + l15;
        float ba0 = (col0 < MAXZ) ? b_atom[col0] : 0.f;
        float ba1 = (col1 < MAXZ) ? b_atom[col1] : 0.f;
#pragma unroll
        for (int at = 0; at < 2; at++)
#pragma unroll
            for (int r = 0; r < 4; r++) {
                int row = n0 + at * 16 + (lane >> 4) * 4 + r;
                if (col0 < MAXZ)
                    out[(size_t)N_ATOMS * 3 + (size_t)row * MAXZ + col0] = am[at][0][r] + ba0;
                if (col1 < MAXZ)
                    out[(size_t)N_ATOMS * 3 + (size_t)row * MAXZ + col1] = am[at][1][r] + ba1;
            }
    }
}

extern "C" void kernel_launch(void* const* d_in, const int* in_sizes, int n_in,
                              void* d_out, int out_size, void* d_ws, size_t ws_size,
                              hipStream_t stream) {
    const float* z         = (const float*)d_in[0];
    const float* frac      = (const float*)d_in[1];
    const int*   types     = (const int*)d_in[2];
    const float* lengths   = (const float*)d_in[4];
    const float* angles    = (const float*)d_in[5];
    const int*   edge_idx  = (const int*)d_in[6];
    const float* atom_emb  = (const float*)d_in[7];
    const float* W_in      = (const float*)d_in[8];
    const float* b_in      = (const float*)d_in[9];
    const float* W_rbf     = (const float*)d_in[10];
    const float* W_edge    = (const float*)d_in[11];
    const float* b_edge    = (const float*)d_in[12];
    const float* W_msg     = (const float*)d_in[13];
    const float* b_msg     = (const float*)d_in[14];
    const float* W_gate    = (const float*)d_in[15];
    const float* W_upd     = (const float*)d_in[16];
    const float* b_upd     = (const float*)d_in[17];
    const float* W_force   = (const float*)d_in[18];
    const float* W_atom    = (const float*)d_in[19];
    const float* b_atom    = (const float*)d_in[20];

    float* out = (float*)d_out;

    // workspace layout
    float* ws = (float*)d_ws;
    size_t off = 0;
    float* cart = ws + off; off += (size_t)N_ATOMS * 3;
    float* agg  = ws + off; off += (size_t)NBLOCK * N_ATOMS * HID;
    float* embW = ws + off; off += MAXZ * HID;
    float* zW   = ws + off; off += N_CRYST * HID;
    float* T    = ws + off; off += (size_t)(TABN + 2) * HID;
    int* cnt    = (int*)(ws + off); off += N_ATOMS;
    int* cursor = (int*)(ws + off); off += N_ATOMS;
    int* perm   = (int*)(ws + off); off += N_EDGES;
    off = (off + 7) & ~(size_t)7;
    ushort_t* ub = (ushort_t*)(ws + off);
    size_t uoff = 0;
    ushort_t* h_bf    = ub + uoff; uoff += (size_t)N_ATOMS * HID;
    ushort_t* Wt_edge = ub + uoff; uoff += 128 * 384;
    ushort_t* Wt_msg  = ub + uoff; uoff += 3 * 128 * 128;
    ushort_t* Wt_gate = ub + uoff; uoff += 3 * 128 * 128;
    ushort_t* Wt_upd  = ub + uoff; uoff += 3 * 128 * 128;
    ushort_t* Wt_atom = ub + uoff; uoff += 128 * 128;

    // 1) zero-init (out force region, agg, cnt)
    k_init<<<(NBLOCK * N_ATOMS * HID + 255) / 256, 256, 0, stream>>>(out, agg, cnt);

    // 2) fused preprocessing: hist | cart | table | weight prep | embW | zW
    k_fuse0<<<F0_ZW, 256, 0, stream>>>(edge_idx, cnt, lengths, angles, frac, cart,
                                       W_rbf, T,
                                       W_edge, W_msg, W_gate, W_upd, W_atom,
                                       Wt_edge, Wt_msg, Wt_gate, Wt_upd, Wt_atom,
                                       atom_emb, W_in, b_in, embW, z, zW);

    // 3) scan
    k_scan<<<1, 256, 0, stream>>>(cnt, cursor);

    // 4) fused scatter + h0
    k_fuse1<<<1280 + (N_ATOMS * HID) / 256, 256, 0, stream>>>(edge_idx, cursor, perm,
                                                              types, embW, zW, h_bf);

    // 5) edge pipeline
    k_edges<<<N_EDGES / ETILE, 512, 0, stream>>>(perm, edge_idx, cart, T, h_bf,
                                                 Wt_edge, b_edge,
                                                 Wt_msg, b_msg, Wt_gate, W_force,
                                                 agg, out);

    // 6) atom-side update + head
    k_atom2<<<N_ATOMS / 32, 256, 0, stream>>>(agg, Wt_upd, b_upd, Wt_atom, b_atom,
                                              h_bf, out);
}